// Round 7
// baseline (291.294 us; speedup 1.0000x reference)
//
#include <hip/hip_runtime.h>
#include <hip/hip_fp16.h>
#include <cstdint>
#include <cstddef>

// Problem constants (match reference)
#define Bn   2
#define Wn   8
#define Nn   10000
#define Fin  5
#define En   80000
#define Hn   128
#define BWn  (Bn*Wn)        // 16
#define ROWS (BWn*Nn)       // 160000
#define MR   (Bn*Nn)        // 20000  (LSTM batch rows)
#define LROWS 32            // LSTM rows per block: MR/32 = 625 blocks exactly

typedef _Float16 half8 __attribute__((ext_vector_type(8)));
typedef float f32x4 __attribute__((ext_vector_type(4)));

#define LOG2E 1.44269504088896f

__device__ __forceinline__ float fast_sigmoid(float x) {
    return __builtin_amdgcn_rcpf(1.f + __builtin_amdgcn_exp2f(-LOG2E * x));
}
__device__ __forceinline__ float fast_tanh(float x) {
    return fmaf(-2.f, __builtin_amdgcn_rcpf(1.f + __builtin_amdgcn_exp2f(2.f * LOG2E * x)), 1.f);
}

// ---------------- fused setup: edge-count + bias-sum + weight-convert + x-transpose -------
// block segments: [0,313) count edges; [313,315) bsum; [315,891) convert weights;
// [891,1016) transpose x -> xt[n][s][f] (80 nodes/block).
__global__ __launch_bounds__(256) void setup_kernel(
    const int* __restrict__ ei, const float* __restrict__ bih, const float* __restrict__ bhh,
    const float* __restrict__ wih, const float* __restrict__ whh,
    const float* __restrict__ g2w, const float* __restrict__ x,
    int* __restrict__ counts, float* __restrict__ bsum,
    _Float16* __restrict__ wif, _Float16* __restrict__ whf,
    _Float16* __restrict__ g2wt, float* __restrict__ xt) {
    __shared__ float buf[6400];
    const int b = blockIdx.x;
    const int tid = threadIdx.x;
    if (b < 313) {
        int e = b * 256 + tid;
        if (e < En) atomicAdd(&counts[ei[En + e]], 1);
    } else if (b < 315) {
        int i = (b - 313) * 256 + tid;
        if (i < 4 * Hn) bsum[i] = bih[i] + bhh[i];
    } else if (b < 891) {
        int i = (b - 315) * 256 + tid;   // < 147456
        if (i < 131072) {
            // wih/whh -> MFMA B-frag layout [ct(32)][kt(4)][lane(64)][j(8)]
            int idx = i & 65535;
            int j = idx & 7, lane = (idx >> 3) & 63, kt = (idx >> 9) & 3, ct = idx >> 11;
            int n = ct * 16 + (lane & 15);
            int k = kt * 32 + (lane >> 4) * 8 + j;
            if (i < 65536) wif[idx] = (_Float16)wih[n * 128 + k];
            else           whf[idx] = (_Float16)whh[n * 128 + k];
        } else {
            int j = i - 131072;          // g2w transpose -> [n][k]
            int n = j >> 7, k = j & 127;
            g2wt[j] = (_Float16)g2w[k * Hn + n];
        }
    } else {
        // transpose x[s][n][f] -> xt[(n*16+s)*5+f], 80 nodes per block
        const int n0 = (b - 891) * 80;
        for (int i = tid; i < 6400; i += 256) {
            int s = i / 400, r = i - s * 400;          // r = node_local*5 + f
            int node = r / 5, f = r - node * 5;
            buf[(node * 16 + s) * 5 + f] = x[((size_t)s * Nn + n0) * 5 + r];
        }
        __syncthreads();
        float* dst = xt + (size_t)n0 * 80;
        for (int i = tid; i < 6400; i += 256) dst[i] = buf[i];
    }
}

enum { CHUNK = 10 };
static_assert(CHUNK * 1024 >= Nn, "scan chunk");

__global__ __launch_bounds__(1024) void scan_kernel(
    const int* __restrict__ counts, int* __restrict__ row_ptr,
    int* __restrict__ fill_ptr, float* __restrict__ dinv) {
    __shared__ int sums[1024];
    const int t = threadIdx.x;
    const int base = t * CHUNK;
    int cnt[CHUNK];
    int s = 0;
    #pragma unroll
    for (int i = 0; i < CHUNK; ++i) {
        int idx = base + i;
        int v = (idx < Nn) ? counts[idx] + 1 : 0;   // +1 self-loop
        cnt[i] = v; s += v;
    }
    sums[t] = s;
    __syncthreads();
    for (int off = 1; off < 1024; off <<= 1) {
        int v = (t >= off) ? sums[t - off] : 0;
        __syncthreads();
        sums[t] += v;
        __syncthreads();
    }
    int excl = (t == 0) ? 0 : sums[t - 1];
    #pragma unroll
    for (int i = 0; i < CHUNK; ++i) {
        int idx = base + i;
        if (idx < Nn) {
            row_ptr[idx] = excl;
            fill_ptr[idx] = excl;
            dinv[idx] = rsqrtf((float)cnt[i]);
            excl += cnt[i];
        }
    }
    if (t == 1023) row_ptr[Nn] = excl;
}

__global__ void fill_kernel(const int* __restrict__ ei,
                            const float* __restrict__ dinv,
                            int* fill_ptr, int* __restrict__ col,
                            float* __restrict__ wgt) {
    int i = blockIdx.x * blockDim.x + threadIdx.x;
    if (i < Nn) {
        int p = atomicAdd(&fill_ptr[i], 1);
        col[p] = i;
        wgt[p] = dinv[i] * dinv[i];
    } else if (i < Nn + En) {
        int e = i - Nn;
        int s = ei[e];
        int d = ei[En + e];
        int p = atomicAdd(&fill_ptr[d], 1);
        col[p] = s;
        wgt[p] = dinv[s] * dinv[d];
    }
}

// ---------------- GCN layer 1 aggregation: contiguous 320 B/edge gather ----------------
__global__ __launch_bounds__(128) void agg_x_kernel(
    const float* __restrict__ xt, const int* __restrict__ row_ptr,
    const int* __restrict__ col, const float* __restrict__ wgt,
    float* __restrict__ aggx) {
    const int n = blockIdx.x;
    const int t = threadIdx.x;
    const int s = t >> 3, f = t & 7;
    if (f >= Fin) return;
    const int start = row_ptr[n], end = row_ptr[n + 1];
    const int off = s * 5 + f;
    float acc = 0.f;
    for (int e = start; e < end; ++e)
        acc = fmaf(wgt[e], xt[(size_t)col[e] * 80 + off], acc);
    aggx[(size_t)n * 80 + off] = acc;   // (n,s) order
}

// ---------------- fused GCN2: h1 = relu(aggx@W1+b1) in-reg, ht = h1 @ g2w (MFMA) ----------
__global__ __launch_bounds__(256) void gcn2_fused_kernel(
    const float* __restrict__ aggx, const float* __restrict__ w1,
    const float* __restrict__ b1, const _Float16* __restrict__ g2wt,
    _Float16* __restrict__ C) {
    __shared__ __align__(16) _Float16 s_buf[128][136];
    __shared__ _Float16 Bs[128][40];
    const int tid = threadIdx.x;
    const int m0 = blockIdx.x * 128;
    {
        const int rg = tid >> 4;
        const int cg = tid & 15;
        float wreg[Fin][8], breg[8];
        #pragma unroll
        for (int k = 0; k < 8; ++k) breg[k] = b1[cg * 8 + k];
        #pragma unroll
        for (int f = 0; f < Fin; ++f)
            #pragma unroll
            for (int k = 0; k < 8; ++k) wreg[f][k] = w1[f * Hn + cg * 8 + k];
        #pragma unroll
        for (int rr = 0; rr < 8; ++rr) {
            const float* ar = aggx + (size_t)(m0 + rg * 8 + rr) * Fin;
            float a[Fin];
            #pragma unroll
            for (int f = 0; f < Fin; ++f) a[f] = ar[f];
            half8 v;
            #pragma unroll
            for (int k = 0; k < 8; ++k) {
                float s = breg[k];
                #pragma unroll
                for (int f = 0; f < Fin; ++f) s = fmaf(a[f], wreg[f][k], s);
                v[k] = (_Float16)fmaxf(s, 0.f);
            }
            *(half8*)&s_buf[rg * 8 + rr][cg * 8] = v;
        }
    }
    __syncthreads();
    const int wave = tid >> 6, lane = tid & 63;
    const int l = lane & 15, q = lane >> 4;
    const int wm = (wave & 1) * 64, wn = (wave >> 1) * 64;
    f32x4 acc[4][4];
    #pragma unroll
    for (int i = 0; i < 4; ++i)
        #pragma unroll
        for (int j = 0; j < 4; ++j) acc[i][j] = (f32x4){0.f, 0.f, 0.f, 0.f};
    for (int kt = 0; kt < 128; kt += 32) {
        #pragma unroll
        for (int j = 0; j < 2; ++j) {
            int idx = tid + j * 256;
            int r = idx >> 2, c = (idx & 3) * 8;
            *(half8*)&Bs[r][c] = *(const half8*)(g2wt + (size_t)r * 128 + kt + c);
        }
        __syncthreads();
        half8 af[4], bf[4];
        #pragma unroll
        for (int i = 0; i < 4; ++i) af[i] = *(const half8*)&s_buf[wm + i * 16 + l][kt + q * 8];
        #pragma unroll
        for (int j = 0; j < 4; ++j) bf[j] = *(const half8*)&Bs[wn + j * 16 + l][q * 8];
        #pragma unroll
        for (int i = 0; i < 4; ++i)
            #pragma unroll
            for (int j = 0; j < 4; ++j)
                acc[i][j] = __builtin_amdgcn_mfma_f32_16x16x32_f16(
                    af[i], bf[j], acc[i][j], 0, 0, 0);
        __syncthreads();
    }
    #pragma unroll
    for (int j = 0; j < 4; ++j) {
        int ccol = wn + j * 16 + l;
        #pragma unroll
        for (int i = 0; i < 4; ++i)
            #pragma unroll
            for (int r = 0; r < 4; ++r)
                s_buf[wm + i * 16 + q * 4 + r][ccol] = (_Float16)acc[i][j][r];
    }
    __syncthreads();
    const size_t base = (size_t)m0 * 128;
    #pragma unroll
    for (int it = 0; it < 8; ++it) {
        int idx = it * 256 + tid;
        int row = idx >> 4, ch = (idx & 15) * 8;
        *(half8*)(C + base + (size_t)row * 128 + ch) = *(const half8*)&s_buf[row][ch];
    }
}

// ---------------- GCN layer 2 aggregation: contiguous 4 KB per edge ----------------
__global__ __launch_bounds__(256) void gcn_agg2_kernel(
    const _Float16* __restrict__ ht, const int* __restrict__ row_ptr,
    const int* __restrict__ col, const float* __restrict__ wgt,
    const float* __restrict__ bias, _Float16* __restrict__ out) {
    const int n = blockIdx.x;
    const int t = threadIdx.x;
    const int s = t >> 4;
    const int g = (t & 15) * 8;
    const int start = row_ptr[n], end = row_ptr[n + 1];
    float acc[8];
    #pragma unroll
    for (int j = 0; j < 8; ++j) acc[j] = 0.f;
    for (int e = start; e < end; ++e) {
        const int c = col[e];
        const float w = wgt[e];
        half8 v = *(const half8*)(ht + ((size_t)c * BWn + s) * Hn + g);
        #pragma unroll
        for (int j = 0; j < 8; ++j) acc[j] = fmaf(w, (float)v[j], acc[j]);
    }
    half8 o;
    #pragma unroll
    for (int j = 0; j < 8; ++j) o[j] = (_Float16)fmaxf(acc[j] + bias[g + j], 0.f);
    *(half8*)(out + ((size_t)n * BWn + s) * Hn + g) = o;
}

// ---------------- fully fused LSTM + decoder ----------------
// grid 625 x 512 threads (8 waves); block owns 32 batch rows. Single sync/step:
// h_lds double-buffered (pointwise writes buf (t+1)&1 while h-pass read buf t&1).
// Decoder epilogue consumes the final h tile straight from LDS.
__global__ __launch_bounds__(512, 1) void lstm_fused3_kernel(
    const _Float16* __restrict__ h2, const _Float16* __restrict__ wif,
    const _Float16* __restrict__ whf, const float* __restrict__ bsum,
    const float* __restrict__ dw1, const float* __restrict__ db1,
    const float* __restrict__ dw2, const float* __restrict__ db2,
    float* __restrict__ out) {
    __shared__ __align__(16) _Float16 x_lds[2][LROWS][144];
    __shared__ __align__(16) _Float16 h_lds[2][LROWS][144];
    const int tid = threadIdx.x;
    const int nw = tid >> 6, lane = tid & 63;
    const int l = lane & 15, q = lane >> 4;
    const int r0 = blockIdx.x * LROWS;
    const int srow = tid >> 4, sch = (tid & 15) * 8;
    const int sgrow = r0 + srow;
    const int sb = (sgrow >= Nn) ? 1 : 0;
    const int sn = sgrow - sb * Nn;
    const _Float16* xbase = h2 + ((size_t)sn * BWn + sb * Wn) * 128 + sch;

    half8 wic[4][4], whc[4][4];
    #pragma unroll
    for (int g = 0; g < 4; ++g) {
        int ct = g * 8 + nw;
        #pragma unroll
        for (int kt = 0; kt < 4; ++kt) {
            wic[g][kt] = *(const half8*)(wif + (((size_t)ct * 4 + kt) * 64 + lane) * 8);
            whc[g][kt] = *(const half8*)(whf + (((size_t)ct * 4 + kt) * 64 + lane) * 8);
        }
    }
    float bias[4];
    #pragma unroll
    for (int g = 0; g < 4; ++g) bias[g] = bsum[g * 128 + nw * 16 + l];
    float c_reg[2][4];
    #pragma unroll
    for (int i = 0; i < 2; ++i)
        #pragma unroll
        for (int r = 0; r < 4; ++r) c_reg[i][r] = 0.f;

    *(half8*)&x_lds[0][srow][sch] = *(const half8*)(xbase);
    __syncthreads();

    for (int t = 0; t < Wn; ++t) {
        half8 xv = {0, 0, 0, 0, 0, 0, 0, 0};
        if (t + 1 < Wn) xv = *(const half8*)(xbase + (size_t)(t + 1) * 128);

        f32x4 acc[2][4];
        #pragma unroll
        for (int i = 0; i < 2; ++i)
            #pragma unroll
            for (int g = 0; g < 4; ++g)
                acc[i][g] = (f32x4){bias[g], bias[g], bias[g], bias[g]};

        #pragma unroll
        for (int kt = 0; kt < 4; ++kt) {
            half8 af[2];
            #pragma unroll
            for (int i = 0; i < 2; ++i)
                af[i] = *(const half8*)&x_lds[t & 1][i * 16 + l][kt * 32 + q * 8];
            #pragma unroll
            for (int i = 0; i < 2; ++i)
                #pragma unroll
                for (int g = 0; g < 4; ++g)
                    acc[i][g] = __builtin_amdgcn_mfma_f32_16x16x32_f16(
                        af[i], wic[g][kt], acc[i][g], 0, 0, 0);
        }
        if (t > 0) {
            #pragma unroll
            for (int kt = 0; kt < 4; ++kt) {
                half8 af[2];
                #pragma unroll
                for (int i = 0; i < 2; ++i)
                    af[i] = *(const half8*)&h_lds[t & 1][i * 16 + l][kt * 32 + q * 8];
                #pragma unroll
                for (int i = 0; i < 2; ++i)
                    #pragma unroll
                    for (int g = 0; g < 4; ++g)
                        acc[i][g] = __builtin_amdgcn_mfma_f32_16x16x32_f16(
                            af[i], whc[g][kt], acc[i][g], 0, 0, 0);
            }
        }
        // pointwise -> other h buffer (no barrier needed before: different buffer,
        // prior readers of (t+1)&1 finished before the sync at end of step t-1)
        #pragma unroll
        for (int i = 0; i < 2; ++i) {
            #pragma unroll
            for (int r = 0; r < 4; ++r) {
                float si = fast_sigmoid(acc[i][0][r]);
                float sf = fast_sigmoid(acc[i][1][r]);
                float tg = fast_tanh(acc[i][2][r]);
                float so = fast_sigmoid(acc[i][3][r]);
                float cn = sf * c_reg[i][r] + si * tg;
                c_reg[i][r] = cn;
                h_lds[(t + 1) & 1][i * 16 + q * 4 + r][nw * 16 + l] =
                    (_Float16)(so * fast_tanh(cn));
            }
        }
        if (t + 1 < Wn) *(half8*)&x_lds[(t + 1) & 1][srow][sch] = xv;
        __syncthreads();
    }

    // ---- decoder epilogue: final h is in h_lds[Wn & 1] == h_lds[0] ----
    #pragma unroll
    for (int rr = 0; rr < 4; ++rr) {
        const int row = nw + rr * 8;
        float d = db1[lane];
        #pragma unroll
        for (int k8 = 0; k8 < 16; ++k8) {
            half8 hv = *(const half8*)&h_lds[0][row][k8 * 8];   // LDS broadcast
            #pragma unroll
            for (int j = 0; j < 8; ++j)
                d = fmaf((float)hv[j], dw1[(k8 * 8 + j) * 64 + lane], d);
        }
        d = fmaxf(d, 0.f);
        float p = d * dw2[lane];
        #pragma unroll
        for (int off = 32; off; off >>= 1) p += __shfl_down(p, off);
        if (lane == 0) out[r0 + row] = p + db2[0];
    }
}

// ---------------- launch ----------------

extern "C" void kernel_launch(void* const* d_in, const int* in_sizes, int n_in,
                              void* d_out, int out_size, void* d_ws, size_t ws_size,
                              hipStream_t stream) {
    const float* x   = (const float*)d_in[0];
    const int*   ei  = (const int*)d_in[1];
    const float* g1w = (const float*)d_in[2];
    const float* g1b = (const float*)d_in[3];
    const float* g2w = (const float*)d_in[4];
    const float* g2b = (const float*)d_in[5];
    const float* wih = (const float*)d_in[6];
    const float* whh = (const float*)d_in[7];
    const float* bih = (const float*)d_in[8];
    const float* bhh = (const float*)d_in[9];
    const float* dw1 = (const float*)d_in[10];
    const float* db1 = (const float*)d_in[11];
    const float* dw2 = (const float*)d_in[12];
    const float* db2 = (const float*)d_in[13];
    float* out = (float*)d_out;

    char* p = (char*)d_ws;
    auto alloc = [&](size_t bytes) {
        char* r = p;
        p += (bytes + 255) & ~(size_t)255;
        return r;
    };
    int*      counts   = (int*)     alloc(Nn * 4);
    int*      row_ptr  = (int*)     alloc((Nn + 1) * 4);
    int*      fill_ptr = (int*)     alloc((Nn + 1) * 4);
    float*    dinv     = (float*)   alloc(Nn * 4);
    float*    bsum     = (float*)   alloc(4 * Hn * 4);
    int*      col      = (int*)     alloc((En + Nn) * 4);
    float*    wgt      = (float*)   alloc((En + Nn) * 4);
    _Float16* wif      = (_Float16*)alloc(512 * 128 * 2);
    _Float16* whf      = (_Float16*)alloc(512 * 128 * 2);
    _Float16* g2wt     = (_Float16*)alloc(128 * 128 * 2);
    float*    xt       = (float*)   alloc((size_t)Nn * 80 * 4);       // 3.2 MB
    float*    aggx     = (float*)   alloc((size_t)ROWS * Fin * 4);    // 3.2 MB
    _Float16* htf      = (_Float16*)alloc((size_t)ROWS * Hn * 2);     // 41 MB
    _Float16* h2f      = (_Float16*)alloc((size_t)ROWS * Hn * 2);     // 41 MB

    // counts must start at 0 (ws is poisoned 0xAA)
    hipMemsetAsync(counts, 0, Nn * 4, stream);

    // ---- fused setup: edge count + bsum + weight convert + x transpose ----
    setup_kernel<<<1016, 256, 0, stream>>>(ei, bih, bhh, wih, whh, g2w, x,
                                           counts, bsum, wif, whf, g2wt, xt);
    scan_kernel<<<1, 1024, 0, stream>>>(counts, row_ptr, fill_ptr, dinv);
    fill_kernel<<<(Nn + En + 255) / 256, 256, 0, stream>>>(ei, dinv, fill_ptr, col, wgt);

    // ---- GCN layer 1 aggregation (contiguous 320 B/edge) ----
    agg_x_kernel<<<Nn, 128, 0, stream>>>(xt, row_ptr, col, wgt, aggx);

    // ---- fused GCN1-transform + GCN2-transform (MFMA) ----
    gcn2_fused_kernel<<<ROWS / 128, 256, 0, stream>>>(aggx, g1w, g1b, g2wt, htf);

    // ---- GCN layer 2 aggregation ----
    gcn_agg2_kernel<<<Nn, 256, 0, stream>>>(htf, row_ptr, col, wgt, g2b, h2f);

    // ---- fully fused LSTM + decoder ----
    lstm_fused3_kernel<<<MR / LROWS, 512, 0, stream>>>(
        h2f, wif, whf, bsum, dw1, db1, dw2, db2, out);
}

// Round 8
// 282.493 us; speedup vs baseline: 1.0312x; 1.0312x over previous
//
#include <hip/hip_runtime.h>
#include <hip/hip_fp16.h>
#include <cstdint>
#include <cstddef>

// Problem constants (match reference)
#define Bn   2
#define Wn   8
#define Nn   10000
#define Fin  5
#define En   80000
#define Hn   128
#define BWn  (Bn*Wn)        // 16
#define ROWS (BWn*Nn)       // 160000
#define MR   (Bn*Nn)        // 20000  (LSTM batch rows)
#define LROWS 32            // LSTM rows per block: MR/32 = 625 blocks exactly

typedef _Float16 half8 __attribute__((ext_vector_type(8)));
typedef float f32x4 __attribute__((ext_vector_type(4)));

#define LOG2E 1.44269504088896f

__device__ __forceinline__ float fast_sigmoid(float x) {
    return __builtin_amdgcn_rcpf(1.f + __builtin_amdgcn_exp2f(-LOG2E * x));
}
__device__ __forceinline__ float fast_tanh(float x) {
    return fmaf(-2.f, __builtin_amdgcn_rcpf(1.f + __builtin_amdgcn_exp2f(2.f * LOG2E * x)), 1.f);
}

// ---------------- fused setup: edge-count + bias-sum + weight-convert + x-transpose -------
// block segments: [0,313) count edges; [313,315) bsum; [315,891) convert weights;
// [891,1016) transpose x -> xt[n][s][f] (80 nodes/block).
__global__ __launch_bounds__(256) void setup_kernel(
    const int* __restrict__ ei, const float* __restrict__ bih, const float* __restrict__ bhh,
    const float* __restrict__ wih, const float* __restrict__ whh,
    const float* __restrict__ g2w, const float* __restrict__ x,
    int* __restrict__ counts, float* __restrict__ bsum,
    _Float16* __restrict__ wif, _Float16* __restrict__ whf,
    _Float16* __restrict__ g2wt, float* __restrict__ xt) {
    __shared__ float buf[6400];
    const int b = blockIdx.x;
    const int tid = threadIdx.x;
    if (b < 313) {
        int e = b * 256 + tid;
        if (e < En) atomicAdd(&counts[ei[En + e]], 1);
    } else if (b < 315) {
        int i = (b - 313) * 256 + tid;
        if (i < 4 * Hn) bsum[i] = bih[i] + bhh[i];
    } else if (b < 891) {
        int i = (b - 315) * 256 + tid;   // < 147456
        if (i < 131072) {
            // wih/whh -> MFMA B-frag layout [ct(32)][kt(4)][lane(64)][j(8)]
            int idx = i & 65535;
            int j = idx & 7, lane = (idx >> 3) & 63, kt = (idx >> 9) & 3, ct = idx >> 11;
            int n = ct * 16 + (lane & 15);
            int k = kt * 32 + (lane >> 4) * 8 + j;
            if (i < 65536) wif[idx] = (_Float16)wih[n * 128 + k];
            else           whf[idx] = (_Float16)whh[n * 128 + k];
        } else {
            int j = i - 131072;          // g2w transpose -> [n][k]
            int n = j >> 7, k = j & 127;
            g2wt[j] = (_Float16)g2w[k * Hn + n];
        }
    } else {
        // transpose x[s][n][f] -> xt[(n*16+s)*5+f], 80 nodes per block
        const int n0 = (b - 891) * 80;
        for (int i = tid; i < 6400; i += 256) {
            int s = i / 400, r = i - s * 400;          // r = node_local*5 + f
            int node = r / 5, f = r - node * 5;
            buf[(node * 16 + s) * 5 + f] = x[((size_t)s * Nn + n0) * 5 + r];
        }
        __syncthreads();
        float* dst = xt + (size_t)n0 * 80;
        for (int i = tid; i < 6400; i += 256) dst[i] = buf[i];
    }
}

enum { CHUNK = 10 };
static_assert(CHUNK * 1024 >= Nn, "scan chunk");

__global__ __launch_bounds__(1024) void scan_kernel(
    const int* __restrict__ counts, int* __restrict__ row_ptr,
    int* __restrict__ fill_ptr, float* __restrict__ dinv) {
    __shared__ int sums[1024];
    const int t = threadIdx.x;
    const int base = t * CHUNK;
    int cnt[CHUNK];
    int s = 0;
    #pragma unroll
    for (int i = 0; i < CHUNK; ++i) {
        int idx = base + i;
        int v = (idx < Nn) ? counts[idx] + 1 : 0;   // +1 self-loop
        cnt[i] = v; s += v;
    }
    sums[t] = s;
    __syncthreads();
    for (int off = 1; off < 1024; off <<= 1) {
        int v = (t >= off) ? sums[t - off] : 0;
        __syncthreads();
        sums[t] += v;
        __syncthreads();
    }
    int excl = (t == 0) ? 0 : sums[t - 1];
    #pragma unroll
    for (int i = 0; i < CHUNK; ++i) {
        int idx = base + i;
        if (idx < Nn) {
            row_ptr[idx] = excl;
            fill_ptr[idx] = excl;
            dinv[idx] = rsqrtf((float)cnt[i]);
            excl += cnt[i];
        }
    }
    if (t == 1023) row_ptr[Nn] = excl;
}

__global__ void fill_kernel(const int* __restrict__ ei,
                            const float* __restrict__ dinv,
                            int* fill_ptr, int* __restrict__ col,
                            float* __restrict__ wgt) {
    int i = blockIdx.x * blockDim.x + threadIdx.x;
    if (i < Nn) {
        int p = atomicAdd(&fill_ptr[i], 1);
        col[p] = i;
        wgt[p] = dinv[i] * dinv[i];
    } else if (i < Nn + En) {
        int e = i - Nn;
        int s = ei[e];
        int d = ei[En + e];
        int p = atomicAdd(&fill_ptr[d], 1);
        col[p] = s;
        wgt[p] = dinv[s] * dinv[d];
    }
}

// ---------------- GCN layer 1 aggregation: contiguous 320 B/edge gather ----------------
__global__ __launch_bounds__(128) void agg_x_kernel(
    const float* __restrict__ xt, const int* __restrict__ row_ptr,
    const int* __restrict__ col, const float* __restrict__ wgt,
    float* __restrict__ aggx) {
    const int n = blockIdx.x;
    const int t = threadIdx.x;
    const int s = t >> 3, f = t & 7;
    if (f >= Fin) return;
    const int start = row_ptr[n], end = row_ptr[n + 1];
    const int off = s * 5 + f;
    float acc = 0.f;
    for (int e = start; e < end; ++e)
        acc = fmaf(wgt[e], xt[(size_t)col[e] * 80 + off], acc);
    aggx[(size_t)n * 80 + off] = acc;   // (n,s) order
}

// ---------------- fused GCN2: h1 = relu(aggx@W1+b1) in-reg, ht = h1 @ g2w (MFMA) ----------
__global__ __launch_bounds__(256) void gcn2_fused_kernel(
    const float* __restrict__ aggx, const float* __restrict__ w1,
    const float* __restrict__ b1, const _Float16* __restrict__ g2wt,
    _Float16* __restrict__ C) {
    __shared__ __align__(16) _Float16 s_buf[128][136];
    __shared__ _Float16 Bs[128][40];
    const int tid = threadIdx.x;
    const int m0 = blockIdx.x * 128;
    {
        const int rg = tid >> 4;
        const int cg = tid & 15;
        float wreg[Fin][8], breg[8];
        #pragma unroll
        for (int k = 0; k < 8; ++k) breg[k] = b1[cg * 8 + k];
        #pragma unroll
        for (int f = 0; f < Fin; ++f)
            #pragma unroll
            for (int k = 0; k < 8; ++k) wreg[f][k] = w1[f * Hn + cg * 8 + k];
        #pragma unroll
        for (int rr = 0; rr < 8; ++rr) {
            const float* ar = aggx + (size_t)(m0 + rg * 8 + rr) * Fin;
            float a[Fin];
            #pragma unroll
            for (int f = 0; f < Fin; ++f) a[f] = ar[f];
            half8 v;
            #pragma unroll
            for (int k = 0; k < 8; ++k) {
                float s = breg[k];
                #pragma unroll
                for (int f = 0; f < Fin; ++f) s = fmaf(a[f], wreg[f][k], s);
                v[k] = (_Float16)fmaxf(s, 0.f);
            }
            *(half8*)&s_buf[rg * 8 + rr][cg * 8] = v;
        }
    }
    __syncthreads();
    const int wave = tid >> 6, lane = tid & 63;
    const int l = lane & 15, q = lane >> 4;
    const int wm = (wave & 1) * 64, wn = (wave >> 1) * 64;
    f32x4 acc[4][4];
    #pragma unroll
    for (int i = 0; i < 4; ++i)
        #pragma unroll
        for (int j = 0; j < 4; ++j) acc[i][j] = (f32x4){0.f, 0.f, 0.f, 0.f};
    for (int kt = 0; kt < 128; kt += 32) {
        #pragma unroll
        for (int j = 0; j < 2; ++j) {
            int idx = tid + j * 256;
            int r = idx >> 2, c = (idx & 3) * 8;
            *(half8*)&Bs[r][c] = *(const half8*)(g2wt + (size_t)r * 128 + kt + c);
        }
        __syncthreads();
        half8 af[4], bf[4];
        #pragma unroll
        for (int i = 0; i < 4; ++i) af[i] = *(const half8*)&s_buf[wm + i * 16 + l][kt + q * 8];
        #pragma unroll
        for (int j = 0; j < 4; ++j) bf[j] = *(const half8*)&Bs[wn + j * 16 + l][q * 8];
        #pragma unroll
        for (int i = 0; i < 4; ++i)
            #pragma unroll
            for (int j = 0; j < 4; ++j)
                acc[i][j] = __builtin_amdgcn_mfma_f32_16x16x32_f16(
                    af[i], bf[j], acc[i][j], 0, 0, 0);
        __syncthreads();
    }
    #pragma unroll
    for (int j = 0; j < 4; ++j) {
        int ccol = wn + j * 16 + l;
        #pragma unroll
        for (int i = 0; i < 4; ++i)
            #pragma unroll
            for (int r = 0; r < 4; ++r)
                s_buf[wm + i * 16 + q * 4 + r][ccol] = (_Float16)acc[i][j][r];
    }
    __syncthreads();
    const size_t base = (size_t)m0 * 128;
    #pragma unroll
    for (int it = 0; it < 8; ++it) {
        int idx = it * 256 + tid;
        int row = idx >> 4, ch = (idx & 15) * 8;
        *(half8*)(C + base + (size_t)row * 128 + ch) = *(const half8*)&s_buf[row][ch];
    }
}

// ---------------- GCN layer 2 aggregation: contiguous 4 KB per edge ----------------
__global__ __launch_bounds__(256) void gcn_agg2_kernel(
    const _Float16* __restrict__ ht, const int* __restrict__ row_ptr,
    const int* __restrict__ col, const float* __restrict__ wgt,
    const float* __restrict__ bias, _Float16* __restrict__ out) {
    const int n = blockIdx.x;
    const int t = threadIdx.x;
    const int s = t >> 4;
    const int g = (t & 15) * 8;
    const int start = row_ptr[n], end = row_ptr[n + 1];
    float acc[8];
    #pragma unroll
    for (int j = 0; j < 8; ++j) acc[j] = 0.f;
    for (int e = start; e < end; ++e) {
        const int c = col[e];
        const float w = wgt[e];
        half8 v = *(const half8*)(ht + ((size_t)c * BWn + s) * Hn + g);
        #pragma unroll
        for (int j = 0; j < 8; ++j) acc[j] = fmaf(w, (float)v[j], acc[j]);
    }
    half8 o;
    #pragma unroll
    for (int j = 0; j < 8; ++j) o[j] = (_Float16)fmaxf(acc[j] + bias[g + j], 0.f);
    *(half8*)(out + ((size_t)n * BWn + s) * Hn + g) = o;
}

// ---------------- fully fused LSTM (round-6 structure: no spills, 2 syncs/step) ----------
// grid 625 x 512 threads (8 waves); block owns 32 batch rows. Wave nw owns h-cols
// nw*16..+15 for ALL 4 gates. Weights register-cached in B-frag layout. x double-
// buffered in LDS; h in LDS; c in registers. Pointwise via v_exp/v_rcp.
__global__ __launch_bounds__(512, 1) void lstm_fused2_kernel(
    const _Float16* __restrict__ h2, const _Float16* __restrict__ wif,
    const _Float16* __restrict__ whf, const float* __restrict__ bsum,
    _Float16* __restrict__ hf) {
    __shared__ __align__(16) _Float16 x_lds[2][LROWS][144];
    __shared__ __align__(16) _Float16 h_lds[LROWS][144];
    const int tid = threadIdx.x;
    const int nw = tid >> 6, lane = tid & 63;
    const int l = lane & 15, q = lane >> 4;
    const int r0 = blockIdx.x * LROWS;
    const int srow = tid >> 4, sch = (tid & 15) * 8;
    const int sgrow = r0 + srow;
    const int sb = (sgrow >= Nn) ? 1 : 0;
    const int sn = sgrow - sb * Nn;
    const _Float16* xbase = h2 + ((size_t)sn * BWn + sb * Wn) * 128 + sch;

    half8 wic[4][4], whc[4][4];
    #pragma unroll
    for (int g = 0; g < 4; ++g) {
        int ct = g * 8 + nw;
        #pragma unroll
        for (int kt = 0; kt < 4; ++kt) {
            wic[g][kt] = *(const half8*)(wif + (((size_t)ct * 4 + kt) * 64 + lane) * 8);
            whc[g][kt] = *(const half8*)(whf + (((size_t)ct * 4 + kt) * 64 + lane) * 8);
        }
    }
    float bias[4];
    #pragma unroll
    for (int g = 0; g < 4; ++g) bias[g] = bsum[g * 128 + nw * 16 + l];
    float c_reg[2][4];
    #pragma unroll
    for (int i = 0; i < 2; ++i)
        #pragma unroll
        for (int r = 0; r < 4; ++r) c_reg[i][r] = 0.f;

    *(half8*)&x_lds[0][srow][sch] = *(const half8*)(xbase);
    __syncthreads();

    for (int t = 0; t < Wn; ++t) {
        half8 xv = {0, 0, 0, 0, 0, 0, 0, 0};
        if (t + 1 < Wn) xv = *(const half8*)(xbase + (size_t)(t + 1) * 128);

        f32x4 acc[2][4];
        #pragma unroll
        for (int i = 0; i < 2; ++i)
            #pragma unroll
            for (int g = 0; g < 4; ++g)
                acc[i][g] = (f32x4){bias[g], bias[g], bias[g], bias[g]};

        #pragma unroll
        for (int kt = 0; kt < 4; ++kt) {
            half8 af[2];
            #pragma unroll
            for (int i = 0; i < 2; ++i)
                af[i] = *(const half8*)&x_lds[t & 1][i * 16 + l][kt * 32 + q * 8];
            #pragma unroll
            for (int i = 0; i < 2; ++i)
                #pragma unroll
                for (int g = 0; g < 4; ++g)
                    acc[i][g] = __builtin_amdgcn_mfma_f32_16x16x32_f16(
                        af[i], wic[g][kt], acc[i][g], 0, 0, 0);
        }
        if (t > 0) {
            #pragma unroll
            for (int kt = 0; kt < 4; ++kt) {
                half8 af[2];
                #pragma unroll
                for (int i = 0; i < 2; ++i)
                    af[i] = *(const half8*)&h_lds[i * 16 + l][kt * 32 + q * 8];
                #pragma unroll
                for (int i = 0; i < 2; ++i)
                    #pragma unroll
                    for (int g = 0; g < 4; ++g)
                        acc[i][g] = __builtin_amdgcn_mfma_f32_16x16x32_f16(
                            af[i], whc[g][kt], acc[i][g], 0, 0, 0);
            }
        }
        __syncthreads();

        #pragma unroll
        for (int i = 0; i < 2; ++i) {
            #pragma unroll
            for (int r = 0; r < 4; ++r) {
                float si = fast_sigmoid(acc[i][0][r]);
                float sf = fast_sigmoid(acc[i][1][r]);
                float tg = fast_tanh(acc[i][2][r]);
                float so = fast_sigmoid(acc[i][3][r]);
                float cn = sf * c_reg[i][r] + si * tg;
                c_reg[i][r] = cn;
                h_lds[i * 16 + q * 4 + r][nw * 16 + l] = (_Float16)(so * fast_tanh(cn));
            }
        }
        if (t + 1 < Wn) *(half8*)&x_lds[(t + 1) & 1][srow][sch] = xv;
        __syncthreads();
    }
    *(half8*)(hf + (size_t)sgrow * 128 + sch) = *(const half8*)&h_lds[srow][sch];
}

// ---------------- decoder ----------------
__global__ __launch_bounds__(256) void decoder_kernel(
    const _Float16* __restrict__ h, const float* __restrict__ w1,
    const float* __restrict__ b1, const float* __restrict__ w2,
    const float* __restrict__ b2, float* __restrict__ out) {
    const int wave = threadIdx.x >> 6;
    const int lane = threadIdx.x & 63;
    const int row = blockIdx.x * 4 + wave;
    if (row >= MR) return;
    const _Float16* hr = h + (size_t)row * Hn;
    float d = b1[lane];
    #pragma unroll 8
    for (int k = 0; k < Hn; ++k) d = fmaf((float)hr[k], w1[k * 64 + lane], d);
    d = fmaxf(d, 0.f);
    float p = d * w2[lane];
    #pragma unroll
    for (int off = 32; off; off >>= 1) p += __shfl_down(p, off);
    if (lane == 0) out[row] = p + b2[0];
}

// ---------------- launch ----------------

extern "C" void kernel_launch(void* const* d_in, const int* in_sizes, int n_in,
                              void* d_out, int out_size, void* d_ws, size_t ws_size,
                              hipStream_t stream) {
    const float* x   = (const float*)d_in[0];
    const int*   ei  = (const int*)d_in[1];
    const float* g1w = (const float*)d_in[2];
    const float* g1b = (const float*)d_in[3];
    const float* g2w = (const float*)d_in[4];
    const float* g2b = (const float*)d_in[5];
    const float* wih = (const float*)d_in[6];
    const float* whh = (const float*)d_in[7];
    const float* bih = (const float*)d_in[8];
    const float* bhh = (const float*)d_in[9];
    const float* dw1 = (const float*)d_in[10];
    const float* db1 = (const float*)d_in[11];
    const float* dw2 = (const float*)d_in[12];
    const float* db2 = (const float*)d_in[13];
    float* out = (float*)d_out;

    char* p = (char*)d_ws;
    auto alloc = [&](size_t bytes) {
        char* r = p;
        p += (bytes + 255) & ~(size_t)255;
        return r;
    };
    int*      counts   = (int*)     alloc(Nn * 4);
    int*      row_ptr  = (int*)     alloc((Nn + 1) * 4);
    int*      fill_ptr = (int*)     alloc((Nn + 1) * 4);
    float*    dinv     = (float*)   alloc(Nn * 4);
    float*    bsum     = (float*)   alloc(4 * Hn * 4);
    int*      col      = (int*)     alloc((En + Nn) * 4);
    float*    wgt      = (float*)   alloc((En + Nn) * 4);
    _Float16* wif      = (_Float16*)alloc(512 * 128 * 2);
    _Float16* whf      = (_Float16*)alloc(512 * 128 * 2);
    _Float16* g2wt     = (_Float16*)alloc(128 * 128 * 2);
    float*    xt       = (float*)   alloc((size_t)Nn * 80 * 4);       // 3.2 MB
    float*    aggx     = (float*)   alloc((size_t)ROWS * Fin * 4);    // 3.2 MB
    _Float16* htf      = (_Float16*)alloc((size_t)ROWS * Hn * 2);     // 41 MB
    _Float16* h2f      = (_Float16*)alloc((size_t)ROWS * Hn * 2);     // 41 MB
    _Float16* hf       = (_Float16*)alloc((size_t)MR * Hn * 2);       // 5.1 MB

    // counts must start at 0 (ws is poisoned 0xAA)
    hipMemsetAsync(counts, 0, Nn * 4, stream);

    // ---- fused setup: edge count + bsum + weight convert + x transpose ----
    setup_kernel<<<1016, 256, 0, stream>>>(ei, bih, bhh, wih, whh, g2w, x,
                                           counts, bsum, wif, whf, g2wt, xt);
    scan_kernel<<<1, 1024, 0, stream>>>(counts, row_ptr, fill_ptr, dinv);
    fill_kernel<<<(Nn + En + 255) / 256, 256, 0, stream>>>(ei, dinv, fill_ptr, col, wgt);

    // ---- GCN layer 1 aggregation (contiguous 320 B/edge) ----
    agg_x_kernel<<<Nn, 128, 0, stream>>>(xt, row_ptr, col, wgt, aggx);

    // ---- fused GCN1-transform + GCN2-transform (MFMA) ----
    gcn2_fused_kernel<<<ROWS / 128, 256, 0, stream>>>(aggx, g1w, g1b, g2wt, htf);

    // ---- GCN layer 2 aggregation ----
    gcn_agg2_kernel<<<Nn, 256, 0, stream>>>(htf, row_ptr, col, wgt, g2b, h2f);

    // ---- fully fused LSTM ----
    lstm_fused2_kernel<<<MR / LROWS, 512, 0, stream>>>(h2f, wif, whf, bsum, hf);

    // ---- decoder ----
    decoder_kernel<<<(MR + 3) / 4, 256, 0, stream>>>(hf, dw1, db1, dw2, db2, out);
}

// Round 9
// 276.252 us; speedup vs baseline: 1.0545x; 1.0226x over previous
//
#include <hip/hip_runtime.h>
#include <hip/hip_fp16.h>
#include <cstdint>
#include <cstddef>

// Problem constants (match reference)
#define Bn   2
#define Wn   8
#define Nn   10000
#define Fin  5
#define En   80000
#define Hn   128
#define BWn  (Bn*Wn)        // 16
#define ROWS (BWn*Nn)       // 160000
#define MR   (Bn*Nn)        // 20000  (LSTM batch rows)
#define LROWS 32            // LSTM rows per block: MR/32 = 625 blocks exactly

typedef _Float16 half8 __attribute__((ext_vector_type(8)));
typedef float f32x4 __attribute__((ext_vector_type(4)));

#define LOG2E 1.44269504088896f

__device__ __forceinline__ float fast_sigmoid(float x) {
    return __builtin_amdgcn_rcpf(1.f + __builtin_amdgcn_exp2f(-LOG2E * x));
}
__device__ __forceinline__ float fast_tanh(float x) {
    return fmaf(-2.f, __builtin_amdgcn_rcpf(1.f + __builtin_amdgcn_exp2f(2.f * LOG2E * x)), 1.f);
}

// ---------------- fused setup: edge-count + bias-sum + weight-convert + x-transpose -------
__global__ __launch_bounds__(256) void setup_kernel(
    const int* __restrict__ ei, const float* __restrict__ bih, const float* __restrict__ bhh,
    const float* __restrict__ wih, const float* __restrict__ whh,
    const float* __restrict__ g2w, const float* __restrict__ x,
    int* __restrict__ counts, float* __restrict__ bsum,
    _Float16* __restrict__ wif, _Float16* __restrict__ whf,
    _Float16* __restrict__ g2wt, float* __restrict__ xt) {
    __shared__ float buf[6400];
    const int b = blockIdx.x;
    const int tid = threadIdx.x;
    if (b < 313) {
        int e = b * 256 + tid;
        if (e < En) atomicAdd(&counts[ei[En + e]], 1);
    } else if (b < 315) {
        int i = (b - 313) * 256 + tid;
        if (i < 4 * Hn) bsum[i] = bih[i] + bhh[i];
    } else if (b < 891) {
        int i = (b - 315) * 256 + tid;   // < 147456
        if (i < 131072) {
            // wih/whh -> MFMA B-frag layout [ct(32)][kt(4)][lane(64)][j(8)]
            int idx = i & 65535;
            int j = idx & 7, lane = (idx >> 3) & 63, kt = (idx >> 9) & 3, ct = idx >> 11;
            int n = ct * 16 + (lane & 15);
            int k = kt * 32 + (lane >> 4) * 8 + j;
            if (i < 65536) wif[idx] = (_Float16)wih[n * 128 + k];
            else           whf[idx] = (_Float16)whh[n * 128 + k];
        } else {
            int j = i - 131072;          // g2w transpose -> [n][k]
            int n = j >> 7, k = j & 127;
            g2wt[j] = (_Float16)g2w[k * Hn + n];
        }
    } else {
        // transpose x[s][n][f] -> xt[(n*16+s)*5+f], 80 nodes per block
        const int n0 = (b - 891) * 80;
        for (int i = tid; i < 6400; i += 256) {
            int s = i / 400, r = i - s * 400;          // r = node_local*5 + f
            int node = r / 5, f = r - node * 5;
            buf[(node * 16 + s) * 5 + f] = x[((size_t)s * Nn + n0) * 5 + r];
        }
        __syncthreads();
        float* dst = xt + (size_t)n0 * 80;
        for (int i = tid; i < 6400; i += 256) dst[i] = buf[i];
    }
}

enum { CHUNK = 10 };
static_assert(CHUNK * 1024 >= Nn, "scan chunk");

__global__ __launch_bounds__(1024) void scan_kernel(
    const int* __restrict__ counts, int* __restrict__ row_ptr,
    int* __restrict__ fill_ptr, float* __restrict__ dinv) {
    __shared__ int sums[1024];
    const int t = threadIdx.x;
    const int base = t * CHUNK;
    int cnt[CHUNK];
    int s = 0;
    #pragma unroll
    for (int i = 0; i < CHUNK; ++i) {
        int idx = base + i;
        int v = (idx < Nn) ? counts[idx] + 1 : 0;   // +1 self-loop
        cnt[i] = v; s += v;
    }
    sums[t] = s;
    __syncthreads();
    for (int off = 1; off < 1024; off <<= 1) {
        int v = (t >= off) ? sums[t - off] : 0;
        __syncthreads();
        sums[t] += v;
        __syncthreads();
    }
    int excl = (t == 0) ? 0 : sums[t - 1];
    #pragma unroll
    for (int i = 0; i < CHUNK; ++i) {
        int idx = base + i;
        if (idx < Nn) {
            row_ptr[idx] = excl;
            fill_ptr[idx] = excl;
            dinv[idx] = rsqrtf((float)cnt[i]);
            excl += cnt[i];
        }
    }
    if (t == 1023) row_ptr[Nn] = excl;
}

__global__ void fill_kernel(const int* __restrict__ ei,
                            const float* __restrict__ dinv,
                            int* fill_ptr, int* __restrict__ col,
                            float* __restrict__ wgt) {
    int i = blockIdx.x * blockDim.x + threadIdx.x;
    if (i < Nn) {
        int p = atomicAdd(&fill_ptr[i], 1);
        col[p] = i;
        wgt[p] = dinv[i] * dinv[i];
    } else if (i < Nn + En) {
        int e = i - Nn;
        int s = ei[e];
        int d = ei[En + e];
        int p = atomicAdd(&fill_ptr[d], 1);
        col[p] = s;
        wgt[p] = dinv[s] * dinv[d];
    }
}

// ---------------- GCN layer 1 aggregation: contiguous 320 B/edge gather, 2-edge MLP ------
__global__ __launch_bounds__(128) void agg_x_kernel(
    const float* __restrict__ xt, const int* __restrict__ row_ptr,
    const int* __restrict__ col, const float* __restrict__ wgt,
    float* __restrict__ aggx) {
    const int n = blockIdx.x;
    const int t = threadIdx.x;
    const int s = t >> 3, f = t & 7;
    if (f >= Fin) return;
    const int start = row_ptr[n], end = row_ptr[n + 1];
    const int off = s * 5 + f;
    float acc0 = 0.f, acc1 = 0.f;
    int e = start;
    for (; e + 1 < end; e += 2) {
        int c0 = col[e], c1 = col[e + 1];
        float w0 = wgt[e], w1 = wgt[e + 1];
        float v0 = xt[(size_t)c0 * 80 + off];
        float v1 = xt[(size_t)c1 * 80 + off];
        acc0 = fmaf(w0, v0, acc0);
        acc1 = fmaf(w1, v1, acc1);
    }
    if (e < end) acc0 = fmaf(wgt[e], xt[(size_t)col[e] * 80 + off], acc0);
    aggx[(size_t)n * 80 + off] = acc0 + acc1;   // (n,s) order
}

// ---------------- fused GCN2: h1 = relu(aggx@W1+b1) in-reg, ht = h1 @ g2w (MFMA) ----------
__global__ __launch_bounds__(256) void gcn2_fused_kernel(
    const float* __restrict__ aggx, const float* __restrict__ w1,
    const float* __restrict__ b1, const _Float16* __restrict__ g2wt,
    _Float16* __restrict__ C) {
    __shared__ __align__(16) _Float16 s_buf[128][136];
    __shared__ _Float16 Bs[128][40];
    const int tid = threadIdx.x;
    const int m0 = blockIdx.x * 128;
    {
        const int rg = tid >> 4;
        const int cg = tid & 15;
        float wreg[Fin][8], breg[8];
        #pragma unroll
        for (int k = 0; k < 8; ++k) breg[k] = b1[cg * 8 + k];
        #pragma unroll
        for (int f = 0; f < Fin; ++f)
            #pragma unroll
            for (int k = 0; k < 8; ++k) wreg[f][k] = w1[f * Hn + cg * 8 + k];
        #pragma unroll
        for (int rr = 0; rr < 8; ++rr) {
            const float* ar = aggx + (size_t)(m0 + rg * 8 + rr) * Fin;
            float a[Fin];
            #pragma unroll
            for (int f = 0; f < Fin; ++f) a[f] = ar[f];
            half8 v;
            #pragma unroll
            for (int k = 0; k < 8; ++k) {
                float s = breg[k];
                #pragma unroll
                for (int f = 0; f < Fin; ++f) s = fmaf(a[f], wreg[f][k], s);
                v[k] = (_Float16)fmaxf(s, 0.f);
            }
            *(half8*)&s_buf[rg * 8 + rr][cg * 8] = v;
        }
    }
    __syncthreads();
    const int wave = tid >> 6, lane = tid & 63;
    const int l = lane & 15, q = lane >> 4;
    const int wm = (wave & 1) * 64, wn = (wave >> 1) * 64;
    f32x4 acc[4][4];
    #pragma unroll
    for (int i = 0; i < 4; ++i)
        #pragma unroll
        for (int j = 0; j < 4; ++j) acc[i][j] = (f32x4){0.f, 0.f, 0.f, 0.f};
    for (int kt = 0; kt < 128; kt += 32) {
        #pragma unroll
        for (int j = 0; j < 2; ++j) {
            int idx = tid + j * 256;
            int r = idx >> 2, c = (idx & 3) * 8;
            *(half8*)&Bs[r][c] = *(const half8*)(g2wt + (size_t)r * 128 + kt + c);
        }
        __syncthreads();
        half8 af[4], bf[4];
        #pragma unroll
        for (int i = 0; i < 4; ++i) af[i] = *(const half8*)&s_buf[wm + i * 16 + l][kt + q * 8];
        #pragma unroll
        for (int j = 0; j < 4; ++j) bf[j] = *(const half8*)&Bs[wn + j * 16 + l][q * 8];
        #pragma unroll
        for (int i = 0; i < 4; ++i)
            #pragma unroll
            for (int j = 0; j < 4; ++j)
                acc[i][j] = __builtin_amdgcn_mfma_f32_16x16x32_f16(
                    af[i], bf[j], acc[i][j], 0, 0, 0);
        __syncthreads();
    }
    #pragma unroll
    for (int j = 0; j < 4; ++j) {
        int ccol = wn + j * 16 + l;
        #pragma unroll
        for (int i = 0; i < 4; ++i)
            #pragma unroll
            for (int r = 0; r < 4; ++r)
                s_buf[wm + i * 16 + q * 4 + r][ccol] = (_Float16)acc[i][j][r];
    }
    __syncthreads();
    const size_t base = (size_t)m0 * 128;
    #pragma unroll
    for (int it = 0; it < 8; ++it) {
        int idx = it * 256 + tid;
        int row = idx >> 4, ch = (idx & 15) * 8;
        *(half8*)(C + base + (size_t)row * 128 + ch) = *(const half8*)&s_buf[row][ch];
    }
}

// ---------------- GCN layer 2 aggregation: contiguous 4 KB per edge, 2-edge MLP ----------
__global__ __launch_bounds__(256) void gcn_agg2_kernel(
    const _Float16* __restrict__ ht, const int* __restrict__ row_ptr,
    const int* __restrict__ col, const float* __restrict__ wgt,
    const float* __restrict__ bias, _Float16* __restrict__ out) {
    const int n = blockIdx.x;
    const int t = threadIdx.x;
    const int s = t >> 4;
    const int g = (t & 15) * 8;
    const int start = row_ptr[n], end = row_ptr[n + 1];
    const size_t lofs = (size_t)s * Hn + g;
    float acc[8];
    #pragma unroll
    for (int j = 0; j < 8; ++j) acc[j] = 0.f;
    int e = start;
    for (; e + 1 < end; e += 2) {
        const int c0 = col[e], c1 = col[e + 1];
        const float w0 = wgt[e], w1 = wgt[e + 1];
        half8 v0 = *(const half8*)(ht + (size_t)c0 * (BWn * Hn) + lofs);
        half8 v1 = *(const half8*)(ht + (size_t)c1 * (BWn * Hn) + lofs);
        #pragma unroll
        for (int j = 0; j < 8; ++j) {
            acc[j] = fmaf(w0, (float)v0[j], acc[j]);
            acc[j] = fmaf(w1, (float)v1[j], acc[j]);
        }
    }
    if (e < end) {
        const float w = wgt[e];
        half8 v = *(const half8*)(ht + (size_t)col[e] * (BWn * Hn) + lofs);
        #pragma unroll
        for (int j = 0; j < 8; ++j) acc[j] = fmaf(w, (float)v[j], acc[j]);
    }
    half8 o;
    #pragma unroll
    for (int j = 0; j < 8; ++j) o[j] = (_Float16)fmaxf(acc[j] + bias[g + j], 0.f);
    *(half8*)(out + (size_t)n * (BWn * Hn) + lofs) = o;
}

// ---------------- fully fused LSTM: single barrier per step (h double-buffered) ----------
// grid 625 x 512 threads (8 waves); block owns 32 batch rows. Wave nw owns h-cols
// nw*16..+15 for ALL 4 gates. Weights register-cached in B-frag layout. x AND h
// double-buffered in LDS: step t reads buf[t&1], pointwise/stage write buf[(t+1)&1],
// ONE barrier at step end. (r7 proved correctness; r7's regression was decoder-fusion
// spill, not this structure. Spill tripwire: WRITE_SIZE should stay ~5 MB.)
__global__ __launch_bounds__(512, 1) void lstm_fused4_kernel(
    const _Float16* __restrict__ h2, const _Float16* __restrict__ wif,
    const _Float16* __restrict__ whf, const float* __restrict__ bsum,
    _Float16* __restrict__ hf) {
    __shared__ __align__(16) _Float16 x_lds[2][LROWS][144];
    __shared__ __align__(16) _Float16 h_lds[2][LROWS][144];
    const int tid = threadIdx.x;
    const int nw = tid >> 6, lane = tid & 63;
    const int l = lane & 15, q = lane >> 4;
    const int r0 = blockIdx.x * LROWS;
    const int srow = tid >> 4, sch = (tid & 15) * 8;
    const int sgrow = r0 + srow;
    const int sb = (sgrow >= Nn) ? 1 : 0;
    const int sn = sgrow - sb * Nn;
    const _Float16* xbase = h2 + ((size_t)sn * BWn + sb * Wn) * 128 + sch;

    half8 wic[4][4], whc[4][4];
    #pragma unroll
    for (int g = 0; g < 4; ++g) {
        int ct = g * 8 + nw;
        #pragma unroll
        for (int kt = 0; kt < 4; ++kt) {
            wic[g][kt] = *(const half8*)(wif + (((size_t)ct * 4 + kt) * 64 + lane) * 8);
            whc[g][kt] = *(const half8*)(whf + (((size_t)ct * 4 + kt) * 64 + lane) * 8);
        }
    }
    float bias[4];
    #pragma unroll
    for (int g = 0; g < 4; ++g) bias[g] = bsum[g * 128 + nw * 16 + l];
    float c_reg[2][4];
    #pragma unroll
    for (int i = 0; i < 2; ++i)
        #pragma unroll
        for (int r = 0; r < 4; ++r) c_reg[i][r] = 0.f;

    *(half8*)&x_lds[0][srow][sch] = *(const half8*)(xbase);
    __syncthreads();

    for (int t = 0; t < Wn; ++t) {
        half8 xv = {0, 0, 0, 0, 0, 0, 0, 0};
        if (t + 1 < Wn) xv = *(const half8*)(xbase + (size_t)(t + 1) * 128);

        f32x4 acc[2][4];
        #pragma unroll
        for (int i = 0; i < 2; ++i)
            #pragma unroll
            for (int g = 0; g < 4; ++g)
                acc[i][g] = (f32x4){bias[g], bias[g], bias[g], bias[g]};

        #pragma unroll
        for (int kt = 0; kt < 4; ++kt) {
            half8 af[2];
            #pragma unroll
            for (int i = 0; i < 2; ++i)
                af[i] = *(const half8*)&x_lds[t & 1][i * 16 + l][kt * 32 + q * 8];
            #pragma unroll
            for (int i = 0; i < 2; ++i)
                #pragma unroll
                for (int g = 0; g < 4; ++g)
                    acc[i][g] = __builtin_amdgcn_mfma_f32_16x16x32_f16(
                        af[i], wic[g][kt], acc[i][g], 0, 0, 0);
        }
        if (t > 0) {
            #pragma unroll
            for (int kt = 0; kt < 4; ++kt) {
                half8 af[2];
                #pragma unroll
                for (int i = 0; i < 2; ++i)
                    af[i] = *(const half8*)&h_lds[t & 1][i * 16 + l][kt * 32 + q * 8];
                #pragma unroll
                for (int i = 0; i < 2; ++i)
                    #pragma unroll
                    for (int g = 0; g < 4; ++g)
                        acc[i][g] = __builtin_amdgcn_mfma_f32_16x16x32_f16(
                            af[i], whc[g][kt], acc[i][g], 0, 0, 0);
            }
        }

        // pointwise -> other h buffer; stage x_{t+1} -> other x buffer; ONE barrier
        #pragma unroll
        for (int i = 0; i < 2; ++i) {
            #pragma unroll
            for (int r = 0; r < 4; ++r) {
                float si = fast_sigmoid(acc[i][0][r]);
                float sf = fast_sigmoid(acc[i][1][r]);
                float tg = fast_tanh(acc[i][2][r]);
                float so = fast_sigmoid(acc[i][3][r]);
                float cn = sf * c_reg[i][r] + si * tg;
                c_reg[i][r] = cn;
                h_lds[(t + 1) & 1][i * 16 + q * 4 + r][nw * 16 + l] =
                    (_Float16)(so * fast_tanh(cn));
            }
        }
        if (t + 1 < Wn) *(half8*)&x_lds[(t + 1) & 1][srow][sch] = xv;
        __syncthreads();
    }
    // final h is in h_lds[Wn & 1] == h_lds[0]
    *(half8*)(hf + (size_t)sgrow * 128 + sch) = *(const half8*)&h_lds[0][srow][sch];
}

// ---------------- decoder ----------------
__global__ __launch_bounds__(256) void decoder_kernel(
    const _Float16* __restrict__ h, const float* __restrict__ w1,
    const float* __restrict__ b1, const float* __restrict__ w2,
    const float* __restrict__ b2, float* __restrict__ out) {
    const int wave = threadIdx.x >> 6;
    const int lane = threadIdx.x & 63;
    const int row = blockIdx.x * 4 + wave;
    if (row >= MR) return;
    const _Float16* hr = h + (size_t)row * Hn;
    float d = b1[lane];
    #pragma unroll 8
    for (int k = 0; k < Hn; ++k) d = fmaf((float)hr[k], w1[k * 64 + lane], d);
    d = fmaxf(d, 0.f);
    float p = d * w2[lane];
    #pragma unroll
    for (int off = 32; off; off >>= 1) p += __shfl_down(p, off);
    if (lane == 0) out[row] = p + b2[0];
}

// ---------------- launch ----------------

extern "C" void kernel_launch(void* const* d_in, const int* in_sizes, int n_in,
                              void* d_out, int out_size, void* d_ws, size_t ws_size,
                              hipStream_t stream) {
    const float* x   = (const float*)d_in[0];
    const int*   ei  = (const int*)d_in[1];
    const float* g1w = (const float*)d_in[2];
    const float* g1b = (const float*)d_in[3];
    const float* g2w = (const float*)d_in[4];
    const float* g2b = (const float*)d_in[5];
    const float* wih = (const float*)d_in[6];
    const float* whh = (const float*)d_in[7];
    const float* bih = (const float*)d_in[8];
    const float* bhh = (const float*)d_in[9];
    const float* dw1 = (const float*)d_in[10];
    const float* db1 = (const float*)d_in[11];
    const float* dw2 = (const float*)d_in[12];
    const float* db2 = (const float*)d_in[13];
    float* out = (float*)d_out;

    char* p = (char*)d_ws;
    auto alloc = [&](size_t bytes) {
        char* r = p;
        p += (bytes + 255) & ~(size_t)255;
        return r;
    };
    int*      counts   = (int*)     alloc(Nn * 4);
    int*      row_ptr  = (int*)     alloc((Nn + 1) * 4);
    int*      fill_ptr = (int*)     alloc((Nn + 1) * 4);
    float*    dinv     = (float*)   alloc(Nn * 4);
    float*    bsum     = (float*)   alloc(4 * Hn * 4);
    int*      col      = (int*)     alloc((En + Nn) * 4);
    float*    wgt      = (float*)   alloc((En + Nn) * 4);
    _Float16* wif      = (_Float16*)alloc(512 * 128 * 2);
    _Float16* whf      = (_Float16*)alloc(512 * 128 * 2);
    _Float16* g2wt     = (_Float16*)alloc(128 * 128 * 2);
    float*    xt       = (float*)   alloc((size_t)Nn * 80 * 4);       // 3.2 MB
    float*    aggx     = (float*)   alloc((size_t)ROWS * Fin * 4);    // 3.2 MB
    _Float16* htf      = (_Float16*)alloc((size_t)ROWS * Hn * 2);     // 41 MB
    _Float16* h2f      = (_Float16*)alloc((size_t)ROWS * Hn * 2);     // 41 MB
    _Float16* hf       = (_Float16*)alloc((size_t)MR * Hn * 2);       // 5.1 MB

    // counts must start at 0 (ws is poisoned 0xAA)
    hipMemsetAsync(counts, 0, Nn * 4, stream);

    // ---- fused setup: edge count + bsum + weight convert + x transpose ----
    setup_kernel<<<1016, 256, 0, stream>>>(ei, bih, bhh, wih, whh, g2w, x,
                                           counts, bsum, wif, whf, g2wt, xt);
    scan_kernel<<<1, 1024, 0, stream>>>(counts, row_ptr, fill_ptr, dinv);
    fill_kernel<<<(Nn + En + 255) / 256, 256, 0, stream>>>(ei, dinv, fill_ptr, col, wgt);

    // ---- GCN layer 1 aggregation (contiguous 320 B/edge) ----
    agg_x_kernel<<<Nn, 128, 0, stream>>>(xt, row_ptr, col, wgt, aggx);

    // ---- fused GCN1-transform + GCN2-transform (MFMA) ----
    gcn2_fused_kernel<<<ROWS / 128, 256, 0, stream>>>(aggx, g1w, g1b, g2wt, htf);

    // ---- GCN layer 2 aggregation ----
    gcn_agg2_kernel<<<Nn, 256, 0, stream>>>(htf, row_ptr, col, wgt, g2b, h2f);

    // ---- fully fused LSTM (single barrier per step) ----
    lstm_fused4_kernel<<<MR / LROWS, 512, 0, stream>>>(h2f, wif, whf, bsum, hf);

    // ---- decoder ----
    decoder_kernel<<<(MR + 3) / 4, 256, 0, stream>>>(hf, dw1, db1, dw2, db2, out);
}

// Round 11
// 267.731 us; speedup vs baseline: 1.0880x; 1.0318x over previous
//
#include <hip/hip_runtime.h>
#include <hip/hip_fp16.h>
#include <cstdint>
#include <cstddef>

// Problem constants (match reference)
#define Bn   2
#define Wn   8
#define Nn   10000
#define Fin  5
#define En   80000
#define Hn   128
#define BWn  (Bn*Wn)        // 16
#define ROWS (BWn*Nn)       // 160000
#define MR   (Bn*Nn)        // 20000  (LSTM batch rows)
#define LROWS 32            // LSTM rows per block: MR/32 = 625 blocks exactly

typedef _Float16 half8 __attribute__((ext_vector_type(8)));
typedef float f32x4 __attribute__((ext_vector_type(4)));

#define LOG2E 1.44269504088896f

__device__ __forceinline__ float fast_sigmoid(float x) {
    return __builtin_amdgcn_rcpf(1.f + __builtin_amdgcn_exp2f(-LOG2E * x));
}
__device__ __forceinline__ float fast_tanh(float x) {
    return fmaf(-2.f, __builtin_amdgcn_rcpf(1.f + __builtin_amdgcn_exp2f(2.f * LOG2E * x)), 1.f);
}

// ---------------- fused setup: edge-count + bias-sum + weight-convert + x-transpose -------
__global__ __launch_bounds__(256) void setup_kernel(
    const int* __restrict__ ei, const float* __restrict__ bih, const float* __restrict__ bhh,
    const float* __restrict__ wih, const float* __restrict__ whh,
    const float* __restrict__ g2w, const float* __restrict__ x,
    int* __restrict__ counts, float* __restrict__ bsum,
    _Float16* __restrict__ wif, _Float16* __restrict__ whf,
    _Float16* __restrict__ g2wt, float* __restrict__ xt) {
    __shared__ float buf[6400];
    const int b = blockIdx.x;
    const int tid = threadIdx.x;
    if (b < 313) {
        int e = b * 256 + tid;
        if (e < En) atomicAdd(&counts[ei[En + e]], 1);
    } else if (b < 315) {
        int i = (b - 313) * 256 + tid;
        if (i < 4 * Hn) bsum[i] = bih[i] + bhh[i];
    } else if (b < 891) {
        int i = (b - 315) * 256 + tid;   // < 147456
        if (i < 131072) {
            // wih/whh -> MFMA B-frag layout [ct(32)][kt(4)][lane(64)][j(8)]
            int idx = i & 65535;
            int j = idx & 7, lane = (idx >> 3) & 63, kt = (idx >> 9) & 3, ct = idx >> 11;
            int n = ct * 16 + (lane & 15);
            int k = kt * 32 + (lane >> 4) * 8 + j;
            if (i < 65536) wif[idx] = (_Float16)wih[n * 128 + k];
            else           whf[idx] = (_Float16)whh[n * 128 + k];
        } else {
            int j = i - 131072;          // g2w transpose -> [n][k]
            int n = j >> 7, k = j & 127;
            g2wt[j] = (_Float16)g2w[k * Hn + n];
        }
    } else {
        // transpose x[s][n][f] -> xt[(n*16+s)*5+f], 80 nodes per block
        const int n0 = (b - 891) * 80;
        for (int i = tid; i < 6400; i += 256) {
            int s = i / 400, r = i - s * 400;          // r = node_local*5 + f
            int node = r / 5, f = r - node * 5;
            buf[(node * 16 + s) * 5 + f] = x[((size_t)s * Nn + n0) * 5 + r];
        }
        __syncthreads();
        float* dst = xt + (size_t)n0 * 80;
        for (int i = tid; i < 6400; i += 256) dst[i] = buf[i];
    }
}

enum { CHUNK = 10 };
static_assert(CHUNK * 1024 >= Nn, "scan chunk");

__global__ __launch_bounds__(1024) void scan_kernel(
    const int* __restrict__ counts, int* __restrict__ row_ptr,
    int* __restrict__ fill_ptr, float* __restrict__ dinv) {
    __shared__ int sums[1024];
    const int t = threadIdx.x;
    const int base = t * CHUNK;
    int cnt[CHUNK];
    int s = 0;
    #pragma unroll
    for (int i = 0; i < CHUNK; ++i) {
        int idx = base + i;
        int v = (idx < Nn) ? counts[idx] + 1 : 0;   // +1 self-loop
        cnt[i] = v; s += v;
    }
    sums[t] = s;
    __syncthreads();
    for (int off = 1; off < 1024; off <<= 1) {
        int v = (t >= off) ? sums[t - off] : 0;
        __syncthreads();
        sums[t] += v;
        __syncthreads();
    }
    int excl = (t == 0) ? 0 : sums[t - 1];
    #pragma unroll
    for (int i = 0; i < CHUNK; ++i) {
        int idx = base + i;
        if (idx < Nn) {
            row_ptr[idx] = excl;
            fill_ptr[idx] = excl;
            dinv[idx] = rsqrtf((float)cnt[i]);
            excl += cnt[i];
        }
    }
    if (t == 1023) row_ptr[Nn] = excl;
}

__global__ void fill_kernel(const int* __restrict__ ei,
                            const float* __restrict__ dinv,
                            int* fill_ptr, int* __restrict__ col,
                            float* __restrict__ wgt) {
    int i = blockIdx.x * blockDim.x + threadIdx.x;
    if (i < Nn) {
        int p = atomicAdd(&fill_ptr[i], 1);
        col[p] = i;
        wgt[p] = dinv[i] * dinv[i];
    } else if (i < Nn + En) {
        int e = i - Nn;
        int s = ei[e];
        int d = ei[En + e];
        int p = atomicAdd(&fill_ptr[d], 1);
        col[p] = s;
        wgt[p] = dinv[s] * dinv[d];
    }
}

// ---------------- GCN layer 1 aggregation: contiguous 320 B/edge gather, 2-edge MLP ------
__global__ __launch_bounds__(128) void agg_x_kernel(
    const float* __restrict__ xt, const int* __restrict__ row_ptr,
    const int* __restrict__ col, const float* __restrict__ wgt,
    float* __restrict__ aggx) {
    const int n = blockIdx.x;
    const int t = threadIdx.x;
    const int s = t >> 3, f = t & 7;
    if (f >= Fin) return;
    const int start = row_ptr[n], end = row_ptr[n + 1];
    const int off = s * 5 + f;
    float acc0 = 0.f, acc1 = 0.f;
    int e = start;
    for (; e + 1 < end; e += 2) {
        int c0 = col[e], c1 = col[e + 1];
        float w0 = wgt[e], w1 = wgt[e + 1];
        float v0 = xt[(size_t)c0 * 80 + off];
        float v1 = xt[(size_t)c1 * 80 + off];
        acc0 = fmaf(w0, v0, acc0);
        acc1 = fmaf(w1, v1, acc1);
    }
    if (e < end) acc0 = fmaf(wgt[e], xt[(size_t)col[e] * 80 + off], acc0);
    aggx[(size_t)n * 80 + off] = acc0 + acc1;   // (n,s) order
}

// ---------------- fused GCN2: h1 = relu(aggx@W1+b1) in-reg, ht = h1 @ g2w (MFMA) ----------
__global__ __launch_bounds__(256) void gcn2_fused_kernel(
    const float* __restrict__ aggx, const float* __restrict__ w1,
    const float* __restrict__ b1, const _Float16* __restrict__ g2wt,
    _Float16* __restrict__ C) {
    __shared__ __align__(16) _Float16 s_buf[128][136];
    __shared__ _Float16 Bs[128][40];
    const int tid = threadIdx.x;
    const int m0 = blockIdx.x * 128;
    {
        const int rg = tid >> 4;
        const int cg = tid & 15;
        float wreg[Fin][8], breg[8];
        #pragma unroll
        for (int k = 0; k < 8; ++k) breg[k] = b1[cg * 8 + k];
        #pragma unroll
        for (int f = 0; f < Fin; ++f)
            #pragma unroll
            for (int k = 0; k < 8; ++k) wreg[f][k] = w1[f * Hn + cg * 8 + k];
        #pragma unroll
        for (int rr = 0; rr < 8; ++rr) {
            const float* ar = aggx + (size_t)(m0 + rg * 8 + rr) * Fin;
            float a[Fin];
            #pragma unroll
            for (int f = 0; f < Fin; ++f) a[f] = ar[f];
            half8 v;
            #pragma unroll
            for (int k = 0; k < 8; ++k) {
                float s = breg[k];
                #pragma unroll
                for (int f = 0; f < Fin; ++f) s = fmaf(a[f], wreg[f][k], s);
                v[k] = (_Float16)fmaxf(s, 0.f);
            }
            *(half8*)&s_buf[rg * 8 + rr][cg * 8] = v;
        }
    }
    __syncthreads();
    const int wave = tid >> 6, lane = tid & 63;
    const int l = lane & 15, q = lane >> 4;
    const int wm = (wave & 1) * 64, wn = (wave >> 1) * 64;
    f32x4 acc[4][4];
    #pragma unroll
    for (int i = 0; i < 4; ++i)
        #pragma unroll
        for (int j = 0; j < 4; ++j) acc[i][j] = (f32x4){0.f, 0.f, 0.f, 0.f};
    for (int kt = 0; kt < 128; kt += 32) {
        #pragma unroll
        for (int j = 0; j < 2; ++j) {
            int idx = tid + j * 256;
            int r = idx >> 2, c = (idx & 3) * 8;
            *(half8*)&Bs[r][c] = *(const half8*)(g2wt + (size_t)r * 128 + kt + c);
        }
        __syncthreads();
        half8 af[4], bf[4];
        #pragma unroll
        for (int i = 0; i < 4; ++i) af[i] = *(const half8*)&s_buf[wm + i * 16 + l][kt + q * 8];
        #pragma unroll
        for (int j = 0; j < 4; ++j) bf[j] = *(const half8*)&Bs[wn + j * 16 + l][q * 8];
        #pragma unroll
        for (int i = 0; i < 4; ++i)
            #pragma unroll
            for (int j = 0; j < 4; ++j)
                acc[i][j] = __builtin_amdgcn_mfma_f32_16x16x32_f16(
                    af[i], bf[j], acc[i][j], 0, 0, 0);
        __syncthreads();
    }
    #pragma unroll
    for (int j = 0; j < 4; ++j) {
        int ccol = wn + j * 16 + l;
        #pragma unroll
        for (int i = 0; i < 4; ++i)
            #pragma unroll
            for (int r = 0; r < 4; ++r)
                s_buf[wm + i * 16 + q * 4 + r][ccol] = (_Float16)acc[i][j][r];
    }
    __syncthreads();
    const size_t base = (size_t)m0 * 128;
    #pragma unroll
    for (int it = 0; it < 8; ++it) {
        int idx = it * 256 + tid;
        int row = idx >> 4, ch = (idx & 15) * 8;
        *(half8*)(C + base + (size_t)row * 128 + ch) = *(const half8*)&s_buf[row][ch];
    }
}

// ---------------- GCN layer 2 aggregation: grid (Nn,2), 128 thr, 4 gathers in flight -----
__global__ __launch_bounds__(128) void gcn_agg2_kernel(
    const _Float16* __restrict__ ht, const int* __restrict__ row_ptr,
    const int* __restrict__ col, const float* __restrict__ wgt,
    const float* __restrict__ bias, _Float16* __restrict__ out) {
    const int n = blockIdx.x;
    const int t = threadIdx.x;
    const int s = blockIdx.y * 8 + (t >> 4);
    const int g = (t & 15) * 8;
    const int start = row_ptr[n], end = row_ptr[n + 1];
    const size_t lofs = (size_t)s * Hn + g;
    float acc[8];
    #pragma unroll
    for (int j = 0; j < 8; ++j) acc[j] = 0.f;
    int e = start;
    for (; e + 3 < end; e += 4) {
        const int c0 = col[e], c1 = col[e + 1], c2 = col[e + 2], c3 = col[e + 3];
        const float w0 = wgt[e], w1 = wgt[e + 1], w2 = wgt[e + 2], w3 = wgt[e + 3];
        half8 v0 = *(const half8*)(ht + (size_t)c0 * (BWn * Hn) + lofs);
        half8 v1 = *(const half8*)(ht + (size_t)c1 * (BWn * Hn) + lofs);
        half8 v2 = *(const half8*)(ht + (size_t)c2 * (BWn * Hn) + lofs);
        half8 v3 = *(const half8*)(ht + (size_t)c3 * (BWn * Hn) + lofs);
        #pragma unroll
        for (int j = 0; j < 8; ++j) {
            acc[j] = fmaf(w0, (float)v0[j], acc[j]);
            acc[j] = fmaf(w1, (float)v1[j], acc[j]);
            acc[j] = fmaf(w2, (float)v2[j], acc[j]);
            acc[j] = fmaf(w3, (float)v3[j], acc[j]);
        }
    }
    for (; e < end; ++e) {
        const float w = wgt[e];
        half8 v = *(const half8*)(ht + (size_t)col[e] * (BWn * Hn) + lofs);
        #pragma unroll
        for (int j = 0; j < 8; ++j) acc[j] = fmaf(w, (float)v[j], acc[j]);
    }
    half8 o;
    #pragma unroll
    for (int j = 0; j < 8; ++j) o[j] = (_Float16)fmaxf(acc[j] + bias[g + j], 0.f);
    *(half8*)(out + (size_t)n * (BWn * Hn) + lofs) = o;
}

// ---------------- fully fused LSTM + decoder (spill-safe, f16 dw1 staging) ----------------
// grid 625 x 512 threads (8 waves); block owns 32 batch rows. Single barrier/step
// (x and h double-buffered). Decoder epilogue: dw1 staged into dead x_lds as F16
// (8192 x 2 B = 16,384 B <= x_lds total 18,432 B — r10's bug was staging f32 = 32 KB,
// which overran x_lds into h_lds and clobbered the final hidden state).
__global__ __launch_bounds__(512, 1) void lstm_fused5_kernel(
    const _Float16* __restrict__ h2, const _Float16* __restrict__ wif,
    const _Float16* __restrict__ whf, const float* __restrict__ bsum,
    const float* __restrict__ dw1, const float* __restrict__ db1,
    const float* __restrict__ dw2, const float* __restrict__ db2,
    float* __restrict__ out) {
    __shared__ __align__(16) _Float16 x_lds[2][LROWS][144];   // 18,432 B
    __shared__ __align__(16) _Float16 h_lds[2][LROWS][144];   // 18,432 B
    const int tid = threadIdx.x;
    const int nw = tid >> 6, lane = tid & 63;
    const int l = lane & 15, q = lane >> 4;
    const int r0 = blockIdx.x * LROWS;
    const int srow = tid >> 4, sch = (tid & 15) * 8;
    const int sgrow = r0 + srow;
    const int sb = (sgrow >= Nn) ? 1 : 0;
    const int sn = sgrow - sb * Nn;
    const _Float16* xbase = h2 + ((size_t)sn * BWn + sb * Wn) * 128 + sch;

    half8 wic[4][4], whc[4][4];
    #pragma unroll
    for (int g = 0; g < 4; ++g) {
        int ct = g * 8 + nw;
        #pragma unroll
        for (int kt = 0; kt < 4; ++kt) {
            wic[g][kt] = *(const half8*)(wif + (((size_t)ct * 4 + kt) * 64 + lane) * 8);
            whc[g][kt] = *(const half8*)(whf + (((size_t)ct * 4 + kt) * 64 + lane) * 8);
        }
    }
    float bias[4];
    #pragma unroll
    for (int g = 0; g < 4; ++g) bias[g] = bsum[g * 128 + nw * 16 + l];
    float c_reg[2][4];
    #pragma unroll
    for (int i = 0; i < 2; ++i)
        #pragma unroll
        for (int r = 0; r < 4; ++r) c_reg[i][r] = 0.f;

    *(half8*)&x_lds[0][srow][sch] = *(const half8*)(xbase);
    __syncthreads();

    for (int t = 0; t < Wn; ++t) {
        half8 xv = {0, 0, 0, 0, 0, 0, 0, 0};
        if (t + 1 < Wn) xv = *(const half8*)(xbase + (size_t)(t + 1) * 128);

        f32x4 acc[2][4];
        #pragma unroll
        for (int i = 0; i < 2; ++i)
            #pragma unroll
            for (int g = 0; g < 4; ++g)
                acc[i][g] = (f32x4){bias[g], bias[g], bias[g], bias[g]};

        #pragma unroll
        for (int kt = 0; kt < 4; ++kt) {
            half8 af[2];
            #pragma unroll
            for (int i = 0; i < 2; ++i)
                af[i] = *(const half8*)&x_lds[t & 1][i * 16 + l][kt * 32 + q * 8];
            #pragma unroll
            for (int i = 0; i < 2; ++i)
                #pragma unroll
                for (int g = 0; g < 4; ++g)
                    acc[i][g] = __builtin_amdgcn_mfma_f32_16x16x32_f16(
                        af[i], wic[g][kt], acc[i][g], 0, 0, 0);
        }
        if (t > 0) {
            #pragma unroll
            for (int kt = 0; kt < 4; ++kt) {
                half8 af[2];
                #pragma unroll
                for (int i = 0; i < 2; ++i)
                    af[i] = *(const half8*)&h_lds[t & 1][i * 16 + l][kt * 32 + q * 8];
                #pragma unroll
                for (int i = 0; i < 2; ++i)
                    #pragma unroll
                    for (int g = 0; g < 4; ++g)
                        acc[i][g] = __builtin_amdgcn_mfma_f32_16x16x32_f16(
                            af[i], whc[g][kt], acc[i][g], 0, 0, 0);
            }
        }

        #pragma unroll
        for (int i = 0; i < 2; ++i) {
            #pragma unroll
            for (int r = 0; r < 4; ++r) {
                float si = fast_sigmoid(acc[i][0][r]);
                float sf = fast_sigmoid(acc[i][1][r]);
                float tg = fast_tanh(acc[i][2][r]);
                float so = fast_sigmoid(acc[i][3][r]);
                float cn = sf * c_reg[i][r] + si * tg;
                c_reg[i][r] = cn;
                h_lds[(t + 1) & 1][i * 16 + q * 4 + r][nw * 16 + l] =
                    (_Float16)(so * fast_tanh(cn));
            }
        }
        if (t + 1 < Wn) *(half8*)&x_lds[(t + 1) & 1][srow][sch] = xv;
        __syncthreads();
    }

    // ---- decoder epilogue: final h in h_lds[0]; dw1 staged into dead x_lds as F16 ----
    _Float16* dw1s = &x_lds[0][0][0];   // 8192 f16 = 16,384 B <= 18,432 B (x_lds only)
    for (int i = tid; i < 8192; i += 512) dw1s[i] = (_Float16)dw1[i];
    __syncthreads();
    const float bd1 = db1[lane];
    const float wd2 = dw2[lane];
    const float bd2 = db2[0];
    #pragma unroll
    for (int rr = 0; rr < 4; ++rr) {
        const int row = nw * 4 + rr;
        float d = bd1;
        #pragma unroll 4
        for (int k = 0; k < Hn; ++k)
            d = fmaf((float)h_lds[0][row][k], (float)dw1s[k * 64 + lane], d);
        d = fmaxf(d, 0.f);
        float pv = d * wd2;
        #pragma unroll
        for (int off = 32; off; off >>= 1) pv += __shfl_down(pv, off);
        if (lane == 0) out[r0 + row] = pv + bd2;
    }
}

// ---------------- launch ----------------

extern "C" void kernel_launch(void* const* d_in, const int* in_sizes, int n_in,
                              void* d_out, int out_size, void* d_ws, size_t ws_size,
                              hipStream_t stream) {
    const float* x   = (const float*)d_in[0];
    const int*   ei  = (const int*)d_in[1];
    const float* g1w = (const float*)d_in[2];
    const float* g1b = (const float*)d_in[3];
    const float* g2w = (const float*)d_in[4];
    const float* g2b = (const float*)d_in[5];
    const float* wih = (const float*)d_in[6];
    const float* whh = (const float*)d_in[7];
    const float* bih = (const float*)d_in[8];
    const float* bhh = (const float*)d_in[9];
    const float* dw1 = (const float*)d_in[10];
    const float* db1 = (const float*)d_in[11];
    const float* dw2 = (const float*)d_in[12];
    const float* db2 = (const float*)d_in[13];
    float* out = (float*)d_out;

    char* p = (char*)d_ws;
    auto alloc = [&](size_t bytes) {
        char* r = p;
        p += (bytes + 255) & ~(size_t)255;
        return r;
    };
    int*      counts   = (int*)     alloc(Nn * 4);
    int*      row_ptr  = (int*)     alloc((Nn + 1) * 4);
    int*      fill_ptr = (int*)     alloc((Nn + 1) * 4);
    float*    dinv     = (float*)   alloc(Nn * 4);
    float*    bsum     = (float*)   alloc(4 * Hn * 4);
    int*      col      = (int*)     alloc((En + Nn) * 4);
    float*    wgt      = (float*)   alloc((En + Nn) * 4);
    _Float16* wif      = (_Float16*)alloc(512 * 128 * 2);
    _Float16* whf      = (_Float16*)alloc(512 * 128 * 2);
    _Float16* g2wt     = (_Float16*)alloc(128 * 128 * 2);
    float*    xt       = (float*)   alloc((size_t)Nn * 80 * 4);       // 3.2 MB
    float*    aggx     = (float*)   alloc((size_t)ROWS * Fin * 4);    // 3.2 MB
    _Float16* htf      = (_Float16*)alloc((size_t)ROWS * Hn * 2);     // 41 MB
    _Float16* h2f      = (_Float16*)alloc((size_t)ROWS * Hn * 2);     // 41 MB

    // counts must start at 0 (ws is poisoned 0xAA)
    hipMemsetAsync(counts, 0, Nn * 4, stream);

    // ---- fused setup: edge count + bsum + weight convert + x transpose ----
    setup_kernel<<<1016, 256, 0, stream>>>(ei, bih, bhh, wih, whh, g2w, x,
                                           counts, bsum, wif, whf, g2wt, xt);
    scan_kernel<<<1, 1024, 0, stream>>>(counts, row_ptr, fill_ptr, dinv);
    fill_kernel<<<(Nn + En + 255) / 256, 256, 0, stream>>>(ei, dinv, fill_ptr, col, wgt);

    // ---- GCN layer 1 aggregation (contiguous 320 B/edge) ----
    agg_x_kernel<<<Nn, 128, 0, stream>>>(xt, row_ptr, col, wgt, aggx);

    // ---- fused GCN1-transform + GCN2-transform (MFMA) ----
    gcn2_fused_kernel<<<ROWS / 128, 256, 0, stream>>>(aggx, g1w, g1b, g2wt, htf);

    // ---- GCN layer 2 aggregation (grid (Nn,2), 4 gathers in flight) ----
    gcn_agg2_kernel<<<dim3(Nn, 2), 128, 0, stream>>>(htf, row_ptr, col, wgt, g2b, h2f);

    // ---- fully fused LSTM + decoder ----
    lstm_fused5_kernel<<<MR / LROWS, 512, 0, stream>>>(
        h2f, wif, whf, bsum, dw1, db1, dw2, db2, out);
}

// Round 12
// 245.636 us; speedup vs baseline: 1.1859x; 1.0899x over previous
//
#include <hip/hip_runtime.h>
#include <hip/hip_fp16.h>
#include <cstdint>
#include <cstddef>

// Problem constants (match reference)
#define Bn   2
#define Wn   8
#define Nn   10000
#define Fin  5
#define En   80000
#define Hn   128
#define BWn  (Bn*Wn)        // 16
#define ROWS (BWn*Nn)       // 160000
#define MR   (Bn*Nn)        // 20000  (LSTM batch rows)
#define LROWS 32            // LSTM rows per block: MR/32 = 625 blocks exactly

typedef _Float16 half8 __attribute__((ext_vector_type(8)));
typedef float f32x4 __attribute__((ext_vector_type(4)));

#define LOG2E 1.44269504088896f

__device__ __forceinline__ float fast_sigmoid(float x) {
    return __builtin_amdgcn_rcpf(1.f + __builtin_amdgcn_exp2f(-LOG2E * x));
}
__device__ __forceinline__ float fast_tanh(float x) {
    return fmaf(-2.f, __builtin_amdgcn_rcpf(1.f + __builtin_amdgcn_exp2f(2.f * LOG2E * x)), 1.f);
}

// ---------------- fused setup: edge-count + bsum + weight-convert + x-transpose ----------
// block segments: [0,313) count edges; [313,315) bsum; [315,891) convert wih/whh/g2w;
// [891,1016) transpose x; [1016,1048) dw1 -> B-frag layout.
__global__ __launch_bounds__(256) void setup_kernel(
    const int* __restrict__ ei, const float* __restrict__ bih, const float* __restrict__ bhh,
    const float* __restrict__ wih, const float* __restrict__ whh,
    const float* __restrict__ g2w, const float* __restrict__ x,
    const float* __restrict__ dw1,
    int* __restrict__ counts, float* __restrict__ bsum,
    _Float16* __restrict__ wif, _Float16* __restrict__ whf,
    _Float16* __restrict__ g2wt, float* __restrict__ xt,
    _Float16* __restrict__ d1f) {
    __shared__ float buf[6400];
    const int b = blockIdx.x;
    const int tid = threadIdx.x;
    if (b < 313) {
        int e = b * 256 + tid;
        if (e < En) atomicAdd(&counts[ei[En + e]], 1);
    } else if (b < 315) {
        int i = (b - 313) * 256 + tid;
        if (i < 4 * Hn) bsum[i] = bih[i] + bhh[i];
    } else if (b < 891) {
        int i = (b - 315) * 256 + tid;   // < 147456
        if (i < 131072) {
            // wih/whh -> MFMA B-frag layout [ct(32)][kt(4)][lane(64)][j(8)]
            int idx = i & 65535;
            int j = idx & 7, lane = (idx >> 3) & 63, kt = (idx >> 9) & 3, ct = idx >> 11;
            int n = ct * 16 + (lane & 15);
            int k = kt * 32 + (lane >> 4) * 8 + j;
            if (i < 65536) wif[idx] = (_Float16)wih[n * 128 + k];
            else           whf[idx] = (_Float16)whh[n * 128 + k];
        } else {
            int j = i - 131072;          // g2w transpose -> [n][k]
            int n = j >> 7, k = j & 127;
            g2wt[j] = (_Float16)g2w[k * Hn + n];
        }
    } else if (b < 1016) {
        // transpose x[s][n][f] -> xt[(n*16+s)*5+f], 80 nodes per block
        const int n0 = (b - 891) * 80;
        for (int i = tid; i < 6400; i += 256) {
            int s = i / 400, r = i - s * 400;          // r = node_local*5 + f
            int node = r / 5, f = r - node * 5;
            buf[(node * 16 + s) * 5 + f] = x[((size_t)s * Nn + n0) * 5 + r];
        }
        __syncthreads();
        float* dst = xt + (size_t)n0 * 80;
        for (int i = tid; i < 6400; i += 256) dst[i] = buf[i];
    } else {
        // dw1 (128 x 64, [k][n]) -> B-frag layout [ct(4)][kt(4)][lane(64)][j(8)]
        int i = (b - 1016) * 256 + tid;   // < 8192
        int j = i & 7, lane = (i >> 3) & 63, kt = (i >> 9) & 3, ct = i >> 11;
        int n = ct * 16 + (lane & 15);                 // unit < 64
        int k = kt * 32 + (lane >> 4) * 8 + j;         // k < 128
        d1f[i] = (_Float16)dw1[k * 64 + n];
    }
}

enum { CHUNK = 10 };
static_assert(CHUNK * 1024 >= Nn, "scan chunk");

__global__ __launch_bounds__(1024) void scan_kernel(
    const int* __restrict__ counts, int* __restrict__ row_ptr,
    int* __restrict__ fill_ptr, float* __restrict__ dinv) {
    __shared__ int sums[1024];
    const int t = threadIdx.x;
    const int base = t * CHUNK;
    int cnt[CHUNK];
    int s = 0;
    #pragma unroll
    for (int i = 0; i < CHUNK; ++i) {
        int idx = base + i;
        int v = (idx < Nn) ? counts[idx] + 1 : 0;   // +1 self-loop
        cnt[i] = v; s += v;
    }
    sums[t] = s;
    __syncthreads();
    for (int off = 1; off < 1024; off <<= 1) {
        int v = (t >= off) ? sums[t - off] : 0;
        __syncthreads();
        sums[t] += v;
        __syncthreads();
    }
    int excl = (t == 0) ? 0 : sums[t - 1];
    #pragma unroll
    for (int i = 0; i < CHUNK; ++i) {
        int idx = base + i;
        if (idx < Nn) {
            row_ptr[idx] = excl;
            fill_ptr[idx] = excl;
            dinv[idx] = rsqrtf((float)cnt[i]);
            excl += cnt[i];
        }
    }
    if (t == 1023) row_ptr[Nn] = excl;
}

__global__ void fill_kernel(const int* __restrict__ ei,
                            const float* __restrict__ dinv,
                            int* fill_ptr, int* __restrict__ col,
                            float* __restrict__ wgt) {
    int i = blockIdx.x * blockDim.x + threadIdx.x;
    if (i < Nn) {
        int p = atomicAdd(&fill_ptr[i], 1);
        col[p] = i;
        wgt[p] = dinv[i] * dinv[i];
    } else if (i < Nn + En) {
        int e = i - Nn;
        int s = ei[e];
        int d = ei[En + e];
        int p = atomicAdd(&fill_ptr[d], 1);
        col[p] = s;
        wgt[p] = dinv[s] * dinv[d];
    }
}

// ---------------- GCN layer 1 aggregation: contiguous 320 B/edge gather, 2-edge MLP ------
__global__ __launch_bounds__(128) void agg_x_kernel(
    const float* __restrict__ xt, const int* __restrict__ row_ptr,
    const int* __restrict__ col, const float* __restrict__ wgt,
    float* __restrict__ aggx) {
    const int n = blockIdx.x;
    const int t = threadIdx.x;
    const int s = t >> 3, f = t & 7;
    if (f >= Fin) return;
    const int start = row_ptr[n], end = row_ptr[n + 1];
    const int off = s * 5 + f;
    float acc0 = 0.f, acc1 = 0.f;
    int e = start;
    for (; e + 1 < end; e += 2) {
        int c0 = col[e], c1 = col[e + 1];
        float w0 = wgt[e], w1 = wgt[e + 1];
        float v0 = xt[(size_t)c0 * 80 + off];
        float v1 = xt[(size_t)c1 * 80 + off];
        acc0 = fmaf(w0, v0, acc0);
        acc1 = fmaf(w1, v1, acc1);
    }
    if (e < end) acc0 = fmaf(wgt[e], xt[(size_t)col[e] * 80 + off], acc0);
    aggx[(size_t)n * 80 + off] = acc0 + acc1;   // (n,s) order
}

// ---------------- fused GCN2: h1 = relu(aggx@W1+b1) in-reg, ht = h1 @ g2w (MFMA) ----------
__global__ __launch_bounds__(256) void gcn2_fused_kernel(
    const float* __restrict__ aggx, const float* __restrict__ w1,
    const float* __restrict__ b1, const _Float16* __restrict__ g2wt,
    _Float16* __restrict__ C) {
    __shared__ __align__(16) _Float16 s_buf[128][136];
    __shared__ _Float16 Bs[128][40];
    const int tid = threadIdx.x;
    const int m0 = blockIdx.x * 128;
    {
        const int rg = tid >> 4;
        const int cg = tid & 15;
        float wreg[Fin][8], breg[8];
        #pragma unroll
        for (int k = 0; k < 8; ++k) breg[k] = b1[cg * 8 + k];
        #pragma unroll
        for (int f = 0; f < Fin; ++f)
            #pragma unroll
            for (int k = 0; k < 8; ++k) wreg[f][k] = w1[f * Hn + cg * 8 + k];
        #pragma unroll
        for (int rr = 0; rr < 8; ++rr) {
            const float* ar = aggx + (size_t)(m0 + rg * 8 + rr) * Fin;
            float a[Fin];
            #pragma unroll
            for (int f = 0; f < Fin; ++f) a[f] = ar[f];
            half8 v;
            #pragma unroll
            for (int k = 0; k < 8; ++k) {
                float s = breg[k];
                #pragma unroll
                for (int f = 0; f < Fin; ++f) s = fmaf(a[f], wreg[f][k], s);
                v[k] = (_Float16)fmaxf(s, 0.f);
            }
            *(half8*)&s_buf[rg * 8 + rr][cg * 8] = v;
        }
    }
    __syncthreads();
    const int wave = tid >> 6, lane = tid & 63;
    const int l = lane & 15, q = lane >> 4;
    const int wm = (wave & 1) * 64, wn = (wave >> 1) * 64;
    f32x4 acc[4][4];
    #pragma unroll
    for (int i = 0; i < 4; ++i)
        #pragma unroll
        for (int j = 0; j < 4; ++j) acc[i][j] = (f32x4){0.f, 0.f, 0.f, 0.f};
    for (int kt = 0; kt < 128; kt += 32) {
        #pragma unroll
        for (int j = 0; j < 2; ++j) {
            int idx = tid + j * 256;
            int r = idx >> 2, c = (idx & 3) * 8;
            *(half8*)&Bs[r][c] = *(const half8*)(g2wt + (size_t)r * 128 + kt + c);
        }
        __syncthreads();
        half8 af[4], bf[4];
        #pragma unroll
        for (int i = 0; i < 4; ++i) af[i] = *(const half8*)&s_buf[wm + i * 16 + l][kt + q * 8];
        #pragma unroll
        for (int j = 0; j < 4; ++j) bf[j] = *(const half8*)&Bs[wn + j * 16 + l][q * 8];
        #pragma unroll
        for (int i = 0; i < 4; ++i)
            #pragma unroll
            for (int j = 0; j < 4; ++j)
                acc[i][j] = __builtin_amdgcn_mfma_f32_16x16x32_f16(
                    af[i], bf[j], acc[i][j], 0, 0, 0);
        __syncthreads();
    }
    #pragma unroll
    for (int j = 0; j < 4; ++j) {
        int ccol = wn + j * 16 + l;
        #pragma unroll
        for (int i = 0; i < 4; ++i)
            #pragma unroll
            for (int r = 0; r < 4; ++r)
                s_buf[wm + i * 16 + q * 4 + r][ccol] = (_Float16)acc[i][j][r];
    }
    __syncthreads();
    const size_t base = (size_t)m0 * 128;
    #pragma unroll
    for (int it = 0; it < 8; ++it) {
        int idx = it * 256 + tid;
        int row = idx >> 4, ch = (idx & 15) * 8;
        *(half8*)(C + base + (size_t)row * 128 + ch) = *(const half8*)&s_buf[row][ch];
    }
}

// ---------------- GCN layer 2 aggregation: grid (Nn,2), 128 thr, 4 gathers in flight -----
__global__ __launch_bounds__(128) void gcn_agg2_kernel(
    const _Float16* __restrict__ ht, const int* __restrict__ row_ptr,
    const int* __restrict__ col, const float* __restrict__ wgt,
    const float* __restrict__ bias, _Float16* __restrict__ out) {
    const int n = blockIdx.x;
    const int t = threadIdx.x;
    const int s = blockIdx.y * 8 + (t >> 4);
    const int g = (t & 15) * 8;
    const int start = row_ptr[n], end = row_ptr[n + 1];
    const size_t lofs = (size_t)s * Hn + g;
    float acc[8];
    #pragma unroll
    for (int j = 0; j < 8; ++j) acc[j] = 0.f;
    int e = start;
    for (; e + 3 < end; e += 4) {
        const int c0 = col[e], c1 = col[e + 1], c2 = col[e + 2], c3 = col[e + 3];
        const float w0 = wgt[e], w1 = wgt[e + 1], w2 = wgt[e + 2], w3 = wgt[e + 3];
        half8 v0 = *(const half8*)(ht + (size_t)c0 * (BWn * Hn) + lofs);
        half8 v1 = *(const half8*)(ht + (size_t)c1 * (BWn * Hn) + lofs);
        half8 v2 = *(const half8*)(ht + (size_t)c2 * (BWn * Hn) + lofs);
        half8 v3 = *(const half8*)(ht + (size_t)c3 * (BWn * Hn) + lofs);
        #pragma unroll
        for (int j = 0; j < 8; ++j) {
            acc[j] = fmaf(w0, (float)v0[j], acc[j]);
            acc[j] = fmaf(w1, (float)v1[j], acc[j]);
            acc[j] = fmaf(w2, (float)v2[j], acc[j]);
            acc[j] = fmaf(w3, (float)v3[j], acc[j]);
        }
    }
    for (; e < end; ++e) {
        const float w = wgt[e];
        half8 v = *(const half8*)(ht + (size_t)col[e] * (BWn * Hn) + lofs);
        #pragma unroll
        for (int j = 0; j < 8; ++j) acc[j] = fmaf(w, (float)v[j], acc[j]);
    }
    half8 o;
    #pragma unroll
    for (int j = 0; j < 8; ++j) o[j] = (_Float16)fmaxf(acc[j] + bias[g + j], 0.f);
    *(half8*)(out + (size_t)n * (BWn * Hn) + lofs) = o;
}

// ---------------- fully fused LSTM + MFMA decoder ----------------
// grid 625 x 512 threads (8 waves); block owns 32 batch rows. Single barrier/step
// (x and h double-buffered). Decoder layer-1 as one MFMA tile per wave:
// wave (mi=w>>2, ni=w&3) computes d[rows mi*16..][units ni*16..] from h_lds A-frags
// + d1f B-frags (global, pre-permuted). relu + *dw2 in C-frag regs, shfl_xor
// row-reduce over 16 units, 4-wave combine via 512 B of dead x_lds.
// (r11's scalar-LDS epilogue cost ~26 us — 1024 ds_read_u16/wave on one LDS pipe.)
__global__ __launch_bounds__(512, 1) void lstm_fused6_kernel(
    const _Float16* __restrict__ h2, const _Float16* __restrict__ wif,
    const _Float16* __restrict__ whf, const float* __restrict__ bsum,
    const _Float16* __restrict__ d1f, const float* __restrict__ db1,
    const float* __restrict__ dw2, const float* __restrict__ db2,
    float* __restrict__ out) {
    __shared__ __align__(16) _Float16 x_lds[2][LROWS][144];   // 18,432 B
    __shared__ __align__(16) _Float16 h_lds[2][LROWS][144];   // 18,432 B
    const int tid = threadIdx.x;
    const int nw = tid >> 6, lane = tid & 63;
    const int l = lane & 15, q = lane >> 4;
    const int r0 = blockIdx.x * LROWS;
    const int srow = tid >> 4, sch = (tid & 15) * 8;
    const int sgrow = r0 + srow;
    const int sb = (sgrow >= Nn) ? 1 : 0;
    const int sn = sgrow - sb * Nn;
    const _Float16* xbase = h2 + ((size_t)sn * BWn + sb * Wn) * 128 + sch;

    half8 wic[4][4], whc[4][4];
    #pragma unroll
    for (int g = 0; g < 4; ++g) {
        int ct = g * 8 + nw;
        #pragma unroll
        for (int kt = 0; kt < 4; ++kt) {
            wic[g][kt] = *(const half8*)(wif + (((size_t)ct * 4 + kt) * 64 + lane) * 8);
            whc[g][kt] = *(const half8*)(whf + (((size_t)ct * 4 + kt) * 64 + lane) * 8);
        }
    }
    float bias[4];
    #pragma unroll
    for (int g = 0; g < 4; ++g) bias[g] = bsum[g * 128 + nw * 16 + l];
    float c_reg[2][4];
    #pragma unroll
    for (int i = 0; i < 2; ++i)
        #pragma unroll
        for (int r = 0; r < 4; ++r) c_reg[i][r] = 0.f;

    *(half8*)&x_lds[0][srow][sch] = *(const half8*)(xbase);
    __syncthreads();

    for (int t = 0; t < Wn; ++t) {
        half8 xv = {0, 0, 0, 0, 0, 0, 0, 0};
        if (t + 1 < Wn) xv = *(const half8*)(xbase + (size_t)(t + 1) * 128);

        f32x4 acc[2][4];
        #pragma unroll
        for (int i = 0; i < 2; ++i)
            #pragma unroll
            for (int g = 0; g < 4; ++g)
                acc[i][g] = (f32x4){bias[g], bias[g], bias[g], bias[g]};

        #pragma unroll
        for (int kt = 0; kt < 4; ++kt) {
            half8 af[2];
            #pragma unroll
            for (int i = 0; i < 2; ++i)
                af[i] = *(const half8*)&x_lds[t & 1][i * 16 + l][kt * 32 + q * 8];
            #pragma unroll
            for (int i = 0; i < 2; ++i)
                #pragma unroll
                for (int g = 0; g < 4; ++g)
                    acc[i][g] = __builtin_amdgcn_mfma_f32_16x16x32_f16(
                        af[i], wic[g][kt], acc[i][g], 0, 0, 0);
        }
        if (t > 0) {
            #pragma unroll
            for (int kt = 0; kt < 4; ++kt) {
                half8 af[2];
                #pragma unroll
                for (int i = 0; i < 2; ++i)
                    af[i] = *(const half8*)&h_lds[t & 1][i * 16 + l][kt * 32 + q * 8];
                #pragma unroll
                for (int i = 0; i < 2; ++i)
                    #pragma unroll
                    for (int g = 0; g < 4; ++g)
                        acc[i][g] = __builtin_amdgcn_mfma_f32_16x16x32_f16(
                            af[i], whc[g][kt], acc[i][g], 0, 0, 0);
            }
        }

        #pragma unroll
        for (int i = 0; i < 2; ++i) {
            #pragma unroll
            for (int r = 0; r < 4; ++r) {
                float si = fast_sigmoid(acc[i][0][r]);
                float sf = fast_sigmoid(acc[i][1][r]);
                float tg = fast_tanh(acc[i][2][r]);
                float so = fast_sigmoid(acc[i][3][r]);
                float cn = sf * c_reg[i][r] + si * tg;
                c_reg[i][r] = cn;
                h_lds[(t + 1) & 1][i * 16 + q * 4 + r][nw * 16 + l] =
                    (_Float16)(so * fast_tanh(cn));
            }
        }
        if (t + 1 < Wn) *(half8*)&x_lds[(t + 1) & 1][srow][sch] = xv;
        __syncthreads();
    }

    // ---- MFMA decoder epilogue: final h in h_lds[0] ----
    const int mi = nw >> 2;           // row tile (2)
    const int ni = nw & 3;            // unit tile (4)
    f32x4 dacc = (f32x4){0.f, 0.f, 0.f, 0.f};
    #pragma unroll
    for (int kt = 0; kt < 4; ++kt) {
        half8 af = *(const half8*)&h_lds[0][mi * 16 + l][kt * 32 + q * 8];
        half8 bf = *(const half8*)(d1f + (((size_t)ni * 4 + kt) * 64 + lane) * 8);
        dacc = __builtin_amdgcn_mfma_f32_16x16x32_f16(af, bf, dacc, 0, 0, 0);
    }
    const int unit = ni * 16 + l;
    const float bd1 = db1[unit];
    const float wd2 = dw2[unit];
    float pr[4];
    #pragma unroll
    for (int r = 0; r < 4; ++r)
        pr[r] = fmaxf(dacc[r] + bd1, 0.f) * wd2;
    // reduce over the 16 units (lanes l=0..15 within each q-group)
    #pragma unroll
    for (int m = 1; m < 16; m <<= 1)
        #pragma unroll
        for (int r = 0; r < 4; ++r)
            pr[r] += __shfl_xor(pr[r], m);
    // 4-wave (ni) combine through dead x_lds
    float* part = (float*)&x_lds[0][0][0];   // 32 rows x 4 ni = 512 B
    if (l == 0) {
        #pragma unroll
        for (int r = 0; r < 4; ++r)
            part[(mi * 16 + q * 4 + r) * 4 + ni] = pr[r];
    }
    __syncthreads();
    if (tid < LROWS) {
        float s = part[tid * 4] + part[tid * 4 + 1] + part[tid * 4 + 2] + part[tid * 4 + 3];
        out[r0 + tid] = s + db2[0];
    }
}

// ---------------- launch ----------------

extern "C" void kernel_launch(void* const* d_in, const int* in_sizes, int n_in,
                              void* d_out, int out_size, void* d_ws, size_t ws_size,
                              hipStream_t stream) {
    const float* x   = (const float*)d_in[0];
    const int*   ei  = (const int*)d_in[1];
    const float* g1w = (const float*)d_in[2];
    const float* g1b = (const float*)d_in[3];
    const float* g2w = (const float*)d_in[4];
    const float* g2b = (const float*)d_in[5];
    const float* wih = (const float*)d_in[6];
    const float* whh = (const float*)d_in[7];
    const float* bih = (const float*)d_in[8];
    const float* bhh = (const float*)d_in[9];
    const float* dw1 = (const float*)d_in[10];
    const float* db1 = (const float*)d_in[11];
    const float* dw2 = (const float*)d_in[12];
    const float* db2 = (const float*)d_in[13];
    float* out = (float*)d_out;

    char* p = (char*)d_ws;
    auto alloc = [&](size_t bytes) {
        char* r = p;
        p += (bytes + 255) & ~(size_t)255;
        return r;
    };
    int*      counts   = (int*)     alloc(Nn * 4);
    int*      row_ptr  = (int*)     alloc((Nn + 1) * 4);
    int*      fill_ptr = (int*)     alloc((Nn + 1) * 4);
    float*    dinv     = (float*)   alloc(Nn * 4);
    float*    bsum     = (float*)   alloc(4 * Hn * 4);
    int*      col      = (int*)     alloc((En + Nn) * 4);
    float*    wgt      = (float*)   alloc((En + Nn) * 4);
    _Float16* wif      = (_Float16*)alloc(512 * 128 * 2);
    _Float16* whf      = (_Float16*)alloc(512 * 128 * 2);
    _Float16* g2wt     = (_Float16*)alloc(128 * 128 * 2);
    _Float16* d1f      = (_Float16*)alloc(64 * 128 * 2);
    float*    xt       = (float*)   alloc((size_t)Nn * 80 * 4);       // 3.2 MB
    float*    aggx     = (float*)   alloc((size_t)ROWS * Fin * 4);    // 3.2 MB
    _Float16* htf      = (_Float16*)alloc((size_t)ROWS * Hn * 2);     // 41 MB
    _Float16* h2f      = (_Float16*)alloc((size_t)ROWS * Hn * 2);     // 41 MB

    // counts must start at 0 (ws is poisoned 0xAA)
    hipMemsetAsync(counts, 0, Nn * 4, stream);

    // ---- fused setup: edge count + bsum + weight convert + x transpose + dw1 frag ----
    setup_kernel<<<1048, 256, 0, stream>>>(ei, bih, bhh, wih, whh, g2w, x, dw1,
                                           counts, bsum, wif, whf, g2wt, xt, d1f);
    scan_kernel<<<1, 1024, 0, stream>>>(counts, row_ptr, fill_ptr, dinv);
    fill_kernel<<<(Nn + En + 255) / 256, 256, 0, stream>>>(ei, dinv, fill_ptr, col, wgt);

    // ---- GCN layer 1 aggregation (contiguous 320 B/edge) ----
    agg_x_kernel<<<Nn, 128, 0, stream>>>(xt, row_ptr, col, wgt, aggx);

    // ---- fused GCN1-transform + GCN2-transform (MFMA) ----
    gcn2_fused_kernel<<<ROWS / 128, 256, 0, stream>>>(aggx, g1w, g1b, g2wt, htf);

    // ---- GCN layer 2 aggregation (grid (Nn,2), 4 gathers in flight) ----
    gcn_agg2_kernel<<<dim3(Nn, 2), 128, 0, stream>>>(htf, row_ptr, col, wgt, g2b, h2f);

    // ---- fully fused LSTM + MFMA decoder ----
    lstm_fused6_kernel<<<MR / LROWS, 512, 0, stream>>>(
        h2f, wif, whf, bsum, d1f, db1, dw2, db2, out);
}

// Round 13
// 244.072 us; speedup vs baseline: 1.1935x; 1.0064x over previous
//
#include <hip/hip_runtime.h>
#include <hip/hip_fp16.h>
#include <cstdint>
#include <cstddef>

// Problem constants (match reference)
#define Bn   2
#define Wn   8
#define Nn   10000
#define Fin  5
#define En   80000
#define Hn   128
#define BWn  (Bn*Wn)        // 16
#define ROWS (BWn*Nn)       // 160000
#define MR   (Bn*Nn)        // 20000  (LSTM batch rows)
#define LROWS 32            // LSTM rows per block: MR/32 = 625 blocks exactly

typedef _Float16 half8 __attribute__((ext_vector_type(8)));
typedef float f32x4 __attribute__((ext_vector_type(4)));

#define LOG2E 1.44269504088896f

__device__ __forceinline__ float fast_sigmoid(float x) {
    return __builtin_amdgcn_rcpf(1.f + __builtin_amdgcn_exp2f(-LOG2E * x));
}
__device__ __forceinline__ float fast_tanh(float x) {
    return fmaf(-2.f, __builtin_amdgcn_rcpf(1.f + __builtin_amdgcn_exp2f(2.f * LOG2E * x)), 1.f);
}

// ---------------- fused setup: edge-count + bsum + weight-convert + x-transpose ----------
// block segments: [0,313) count edges; [313,315) bsum; [315,891) convert wih/whh/g2w;
// [891,1016) transpose x; [1016,1048) dw1 -> B-frag layout.
__global__ __launch_bounds__(256) void setup_kernel(
    const int* __restrict__ ei, const float* __restrict__ bih, const float* __restrict__ bhh,
    const float* __restrict__ wih, const float* __restrict__ whh,
    const float* __restrict__ g2w, const float* __restrict__ x,
    const float* __restrict__ dw1,
    int* __restrict__ counts, float* __restrict__ bsum,
    _Float16* __restrict__ wif, _Float16* __restrict__ whf,
    _Float16* __restrict__ g2wt, float* __restrict__ xt,
    _Float16* __restrict__ d1f) {
    __shared__ float buf[6400];
    const int b = blockIdx.x;
    const int tid = threadIdx.x;
    if (b < 313) {
        int e = b * 256 + tid;
        if (e < En) atomicAdd(&counts[ei[En + e]], 1);
    } else if (b < 315) {
        int i = (b - 313) * 256 + tid;
        if (i < 4 * Hn) bsum[i] = bih[i] + bhh[i];
    } else if (b < 891) {
        int i = (b - 315) * 256 + tid;   // < 147456
        if (i < 131072) {
            // wih/whh -> MFMA B-frag layout [ct(32)][kt(4)][lane(64)][j(8)]
            int idx = i & 65535;
            int j = idx & 7, lane = (idx >> 3) & 63, kt = (idx >> 9) & 3, ct = idx >> 11;
            int n = ct * 16 + (lane & 15);
            int k = kt * 32 + (lane >> 4) * 8 + j;
            if (i < 65536) wif[idx] = (_Float16)wih[n * 128 + k];
            else           whf[idx] = (_Float16)whh[n * 128 + k];
        } else {
            int j = i - 131072;          // g2w transpose -> [n][k]
            int n = j >> 7, k = j & 127;
            g2wt[j] = (_Float16)g2w[k * Hn + n];
        }
    } else if (b < 1016) {
        // transpose x[s][n][f] -> xt[(n*16+s)*5+f], 80 nodes per block
        const int n0 = (b - 891) * 80;
        for (int i = tid; i < 6400; i += 256) {
            int s = i / 400, r = i - s * 400;          // r = node_local*5 + f
            int node = r / 5, f = r - node * 5;
            buf[(node * 16 + s) * 5 + f] = x[((size_t)s * Nn + n0) * 5 + r];
        }
        __syncthreads();
        float* dst = xt + (size_t)n0 * 80;
        for (int i = tid; i < 6400; i += 256) dst[i] = buf[i];
    } else {
        // dw1 (128 x 64, [k][n]) -> B-frag layout [ct(4)][kt(4)][lane(64)][j(8)]
        int i = (b - 1016) * 256 + tid;   // < 8192
        int j = i & 7, lane = (i >> 3) & 63, kt = (i >> 9) & 3, ct = i >> 11;
        int n = ct * 16 + (lane & 15);                 // unit < 64
        int k = kt * 32 + (lane >> 4) * 8 + j;         // k < 128
        d1f[i] = (_Float16)dw1[k * 64 + n];
    }
}

enum { CHUNK = 10 };
static_assert(CHUNK * 1024 >= Nn, "scan chunk");

__global__ __launch_bounds__(1024) void scan_kernel(
    const int* __restrict__ counts, int* __restrict__ row_ptr,
    int* __restrict__ fill_ptr, float* __restrict__ dinv) {
    __shared__ int sums[1024];
    const int t = threadIdx.x;
    const int base = t * CHUNK;
    int cnt[CHUNK];
    int s = 0;
    #pragma unroll
    for (int i = 0; i < CHUNK; ++i) {
        int idx = base + i;
        int v = (idx < Nn) ? counts[idx] + 1 : 0;   // +1 self-loop
        cnt[i] = v; s += v;
    }
    sums[t] = s;
    __syncthreads();
    for (int off = 1; off < 1024; off <<= 1) {
        int v = (t >= off) ? sums[t - off] : 0;
        __syncthreads();
        sums[t] += v;
        __syncthreads();
    }
    int excl = (t == 0) ? 0 : sums[t - 1];
    #pragma unroll
    for (int i = 0; i < CHUNK; ++i) {
        int idx = base + i;
        if (idx < Nn) {
            row_ptr[idx] = excl;
            fill_ptr[idx] = excl;
            dinv[idx] = rsqrtf((float)cnt[i]);
            excl += cnt[i];
        }
    }
    if (t == 1023) row_ptr[Nn] = excl;
}

__global__ void fill_kernel(const int* __restrict__ ei,
                            const float* __restrict__ dinv,
                            int* fill_ptr, int* __restrict__ col,
                            float* __restrict__ wgt) {
    int i = blockIdx.x * blockDim.x + threadIdx.x;
    if (i < Nn) {
        int p = atomicAdd(&fill_ptr[i], 1);
        col[p] = i;
        wgt[p] = dinv[i] * dinv[i];
    } else if (i < Nn + En) {
        int e = i - Nn;
        int s = ei[e];
        int d = ei[En + e];
        int p = atomicAdd(&fill_ptr[d], 1);
        col[p] = s;
        wgt[p] = dinv[s] * dinv[d];
    }
}

// ---------------- fused GCN: agg_x gather (CSR) + h1 transform + GCN2 MFMA ----------------
// Block covers rows m0..m0+127 = nodes n0..n0+7 x 16 slices ((n,s) order).
// Phase 0: gather aggx for the block's 8 nodes into LDS (contiguous 320 B/edge reads).
// Phase 1: h1 = relu(agg@W1+b1) microtile -> s_buf. Phase 2: MFMA vs g2wt. Phase 3: store.
__global__ __launch_bounds__(256) void gcn2_fused_kernel(
    const float* __restrict__ xt, const int* __restrict__ row_ptr,
    const int* __restrict__ col, const float* __restrict__ wgt,
    const float* __restrict__ w1, const float* __restrict__ b1,
    const _Float16* __restrict__ g2wt, _Float16* __restrict__ C) {
    __shared__ float agg_lds[128 * 5];                  // 10,240 B
    __shared__ __align__(16) _Float16 s_buf[128][136];
    __shared__ _Float16 Bs[128][40];
    const int tid = threadIdx.x;
    const int m0 = blockIdx.x * 128;
    const int n0 = m0 >> 4;                             // 8 nodes per block
    // ---- phase 0: CSR gather, 32 threads per node ----
    {
        const int nl = tid >> 5;
        const int it = tid & 31;                        // items it, it+32, it+64(<80)
        const int n = n0 + nl;
        const int start = row_ptr[n], end = row_ptr[n + 1];
        float a0 = 0.f, a1 = 0.f, a2 = 0.f;
        for (int e = start; e < end; ++e) {
            const float w = wgt[e];
            const float* src = xt + (size_t)col[e] * 80;
            a0 = fmaf(w, src[it], a0);
            a1 = fmaf(w, src[it + 32], a1);
            if (it < 16) a2 = fmaf(w, src[it + 64], a2);
        }
        agg_lds[nl * 80 + it] = a0;
        agg_lds[nl * 80 + it + 32] = a1;
        if (it < 16) agg_lds[nl * 80 + it + 64] = a2;
    }
    __syncthreads();
    // ---- phase 1: h1 microtile 8 rows x 8 cols per thread (agg from LDS) ----
    {
        const int rg = tid >> 4;
        const int cg = tid & 15;
        float wreg[Fin][8], breg[8];
        #pragma unroll
        for (int k = 0; k < 8; ++k) breg[k] = b1[cg * 8 + k];
        #pragma unroll
        for (int f = 0; f < Fin; ++f)
            #pragma unroll
            for (int k = 0; k < 8; ++k) wreg[f][k] = w1[f * Hn + cg * 8 + k];
        #pragma unroll
        for (int rr = 0; rr < 8; ++rr) {
            const float* ar = &agg_lds[(rg * 8 + rr) * Fin];
            float a[Fin];
            #pragma unroll
            for (int f = 0; f < Fin; ++f) a[f] = ar[f];
            half8 v;
            #pragma unroll
            for (int k = 0; k < 8; ++k) {
                float s = breg[k];
                #pragma unroll
                for (int f = 0; f < Fin; ++f) s = fmaf(a[f], wreg[f][k], s);
                v[k] = (_Float16)fmaxf(s, 0.f);
            }
            *(half8*)&s_buf[rg * 8 + rr][cg * 8] = v;
        }
    }
    __syncthreads();
    // ---- phase 2: MFMA vs g2wt ----
    const int wave = tid >> 6, lane = tid & 63;
    const int l = lane & 15, q = lane >> 4;
    const int wm = (wave & 1) * 64, wn = (wave >> 1) * 64;
    f32x4 acc[4][4];
    #pragma unroll
    for (int i = 0; i < 4; ++i)
        #pragma unroll
        for (int j = 0; j < 4; ++j) acc[i][j] = (f32x4){0.f, 0.f, 0.f, 0.f};
    for (int kt = 0; kt < 128; kt += 32) {
        #pragma unroll
        for (int j = 0; j < 2; ++j) {
            int idx = tid + j * 256;
            int r = idx >> 2, c = (idx & 3) * 8;
            *(half8*)&Bs[r][c] = *(const half8*)(g2wt + (size_t)r * 128 + kt + c);
        }
        __syncthreads();
        half8 af[4], bf[4];
        #pragma unroll
        for (int i = 0; i < 4; ++i) af[i] = *(const half8*)&s_buf[wm + i * 16 + l][kt + q * 8];
        #pragma unroll
        for (int j = 0; j < 4; ++j) bf[j] = *(const half8*)&Bs[wn + j * 16 + l][q * 8];
        #pragma unroll
        for (int i = 0; i < 4; ++i)
            #pragma unroll
            for (int j = 0; j < 4; ++j)
                acc[i][j] = __builtin_amdgcn_mfma_f32_16x16x32_f16(
                    af[i], bf[j], acc[i][j], 0, 0, 0);
        __syncthreads();
    }
    // ---- phase 3: stage C through s_buf, contiguous stores ----
    #pragma unroll
    for (int j = 0; j < 4; ++j) {
        int ccol = wn + j * 16 + l;
        #pragma unroll
        for (int i = 0; i < 4; ++i)
            #pragma unroll
            for (int r = 0; r < 4; ++r)
                s_buf[wm + i * 16 + q * 4 + r][ccol] = (_Float16)acc[i][j][r];
    }
    __syncthreads();
    const size_t base = (size_t)m0 * 128;
    #pragma unroll
    for (int it = 0; it < 8; ++it) {
        int idx = it * 256 + tid;
        int row = idx >> 4, ch = (idx & 15) * 8;
        *(half8*)(C + base + (size_t)row * 128 + ch) = *(const half8*)&s_buf[row][ch];
    }
}

// ---------------- GCN layer 2 aggregation: grid (Nn,4), 64 thr (1 wave), unroll 4 --------
__global__ __launch_bounds__(64) void gcn_agg2_kernel(
    const _Float16* __restrict__ ht, const int* __restrict__ row_ptr,
    const int* __restrict__ col, const float* __restrict__ wgt,
    const float* __restrict__ bias, _Float16* __restrict__ out) {
    const int n = blockIdx.x;
    const int t = threadIdx.x;
    const int s = blockIdx.y * 4 + (t >> 4);
    const int g = (t & 15) * 8;
    const int start = row_ptr[n], end = row_ptr[n + 1];
    const size_t lofs = (size_t)s * Hn + g;
    float acc[8];
    #pragma unroll
    for (int j = 0; j < 8; ++j) acc[j] = 0.f;
    int e = start;
    for (; e + 3 < end; e += 4) {
        const int c0 = col[e], c1 = col[e + 1], c2 = col[e + 2], c3 = col[e + 3];
        const float w0 = wgt[e], w1 = wgt[e + 1], w2 = wgt[e + 2], w3 = wgt[e + 3];
        half8 v0 = *(const half8*)(ht + (size_t)c0 * (BWn * Hn) + lofs);
        half8 v1 = *(const half8*)(ht + (size_t)c1 * (BWn * Hn) + lofs);
        half8 v2 = *(const half8*)(ht + (size_t)c2 * (BWn * Hn) + lofs);
        half8 v3 = *(const half8*)(ht + (size_t)c3 * (BWn * Hn) + lofs);
        #pragma unroll
        for (int j = 0; j < 8; ++j) {
            acc[j] = fmaf(w0, (float)v0[j], acc[j]);
            acc[j] = fmaf(w1, (float)v1[j], acc[j]);
            acc[j] = fmaf(w2, (float)v2[j], acc[j]);
            acc[j] = fmaf(w3, (float)v3[j], acc[j]);
        }
    }
    for (; e < end; ++e) {
        const float w = wgt[e];
        half8 v = *(const half8*)(ht + (size_t)col[e] * (BWn * Hn) + lofs);
        #pragma unroll
        for (int j = 0; j < 8; ++j) acc[j] = fmaf(w, (float)v[j], acc[j]);
    }
    half8 o;
    #pragma unroll
    for (int j = 0; j < 8; ++j) o[j] = (_Float16)fmaxf(acc[j] + bias[g + j], 0.f);
    *(half8*)(out + (size_t)n * (BWn * Hn) + lofs) = o;
}

// ---------------- fully fused LSTM + MFMA decoder ----------------
__global__ __launch_bounds__(512, 1) void lstm_fused6_kernel(
    const _Float16* __restrict__ h2, const _Float16* __restrict__ wif,
    const _Float16* __restrict__ whf, const float* __restrict__ bsum,
    const _Float16* __restrict__ d1f, const float* __restrict__ db1,
    const float* __restrict__ dw2, const float* __restrict__ db2,
    float* __restrict__ out) {
    __shared__ __align__(16) _Float16 x_lds[2][LROWS][144];   // 18,432 B
    __shared__ __align__(16) _Float16 h_lds[2][LROWS][144];   // 18,432 B
    const int tid = threadIdx.x;
    const int nw = tid >> 6, lane = tid & 63;
    const int l = lane & 15, q = lane >> 4;
    const int r0 = blockIdx.x * LROWS;
    const int srow = tid >> 4, sch = (tid & 15) * 8;
    const int sgrow = r0 + srow;
    const int sb = (sgrow >= Nn) ? 1 : 0;
    const int sn = sgrow - sb * Nn;
    const _Float16* xbase = h2 + ((size_t)sn * BWn + sb * Wn) * 128 + sch;

    half8 wic[4][4], whc[4][4];
    #pragma unroll
    for (int g = 0; g < 4; ++g) {
        int ct = g * 8 + nw;
        #pragma unroll
        for (int kt = 0; kt < 4; ++kt) {
            wic[g][kt] = *(const half8*)(wif + (((size_t)ct * 4 + kt) * 64 + lane) * 8);
            whc[g][kt] = *(const half8*)(whf + (((size_t)ct * 4 + kt) * 64 + lane) * 8);
        }
    }
    float bias[4];
    #pragma unroll
    for (int g = 0; g < 4; ++g) bias[g] = bsum[g * 128 + nw * 16 + l];
    float c_reg[2][4];
    #pragma unroll
    for (int i = 0; i < 2; ++i)
        #pragma unroll
        for (int r = 0; r < 4; ++r) c_reg[i][r] = 0.f;

    *(half8*)&x_lds[0][srow][sch] = *(const half8*)(xbase);
    __syncthreads();

    for (int t = 0; t < Wn; ++t) {
        half8 xv = {0, 0, 0, 0, 0, 0, 0, 0};
        if (t + 1 < Wn) xv = *(const half8*)(xbase + (size_t)(t + 1) * 128);

        f32x4 acc[2][4];
        #pragma unroll
        for (int i = 0; i < 2; ++i)
            #pragma unroll
            for (int g = 0; g < 4; ++g)
                acc[i][g] = (f32x4){bias[g], bias[g], bias[g], bias[g]};

        #pragma unroll
        for (int kt = 0; kt < 4; ++kt) {
            half8 af[2];
            #pragma unroll
            for (int i = 0; i < 2; ++i)
                af[i] = *(const half8*)&x_lds[t & 1][i * 16 + l][kt * 32 + q * 8];
            #pragma unroll
            for (int i = 0; i < 2; ++i)
                #pragma unroll
                for (int g = 0; g < 4; ++g)
                    acc[i][g] = __builtin_amdgcn_mfma_f32_16x16x32_f16(
                        af[i], wic[g][kt], acc[i][g], 0, 0, 0);
        }
        if (t > 0) {
            #pragma unroll
            for (int kt = 0; kt < 4; ++kt) {
                half8 af[2];
                #pragma unroll
                for (int i = 0; i < 2; ++i)
                    af[i] = *(const half8*)&h_lds[t & 1][i * 16 + l][kt * 32 + q * 8];
                #pragma unroll
                for (int i = 0; i < 2; ++i)
                    #pragma unroll
                    for (int g = 0; g < 4; ++g)
                        acc[i][g] = __builtin_amdgcn_mfma_f32_16x16x32_f16(
                            af[i], whc[g][kt], acc[i][g], 0, 0, 0);
            }
        }

        #pragma unroll
        for (int i = 0; i < 2; ++i) {
            #pragma unroll
            for (int r = 0; r < 4; ++r) {
                float si = fast_sigmoid(acc[i][0][r]);
                float sf = fast_sigmoid(acc[i][1][r]);
                float tg = fast_tanh(acc[i][2][r]);
                float so = fast_sigmoid(acc[i][3][r]);
                float cn = sf * c_reg[i][r] + si * tg;
                c_reg[i][r] = cn;
                h_lds[(t + 1) & 1][i * 16 + q * 4 + r][nw * 16 + l] =
                    (_Float16)(so * fast_tanh(cn));
            }
        }
        if (t + 1 < Wn) *(half8*)&x_lds[(t + 1) & 1][srow][sch] = xv;
        __syncthreads();
    }

    // ---- MFMA decoder epilogue: final h in h_lds[0] ----
    const int mi = nw >> 2;           // row tile (2)
    const int ni = nw & 3;            // unit tile (4)
    f32x4 dacc = (f32x4){0.f, 0.f, 0.f, 0.f};
    #pragma unroll
    for (int kt = 0; kt < 4; ++kt) {
        half8 af = *(const half8*)&h_lds[0][mi * 16 + l][kt * 32 + q * 8];
        half8 bf = *(const half8*)(d1f + (((size_t)ni * 4 + kt) * 64 + lane) * 8);
        dacc = __builtin_amdgcn_mfma_f32_16x16x32_f16(af, bf, dacc, 0, 0, 0);
    }
    const int unit = ni * 16 + l;
    const float bd1 = db1[unit];
    const float wd2 = dw2[unit];
    float pr[4];
    #pragma unroll
    for (int r = 0; r < 4; ++r)
        pr[r] = fmaxf(dacc[r] + bd1, 0.f) * wd2;
    #pragma unroll
    for (int m = 1; m < 16; m <<= 1)
        #pragma unroll
        for (int r = 0; r < 4; ++r)
            pr[r] += __shfl_xor(pr[r], m);
    float* part = (float*)&x_lds[0][0][0];   // 32 rows x 4 ni = 512 B (x_lds dead)
    if (l == 0) {
        #pragma unroll
        for (int r = 0; r < 4; ++r)
            part[(mi * 16 + q * 4 + r) * 4 + ni] = pr[r];
    }
    __syncthreads();
    if (tid < LROWS) {
        float s = part[tid * 4] + part[tid * 4 + 1] + part[tid * 4 + 2] + part[tid * 4 + 3];
        out[r0 + tid] = s + db2[0];
    }
}

// ---------------- launch ----------------

extern "C" void kernel_launch(void* const* d_in, const int* in_sizes, int n_in,
                              void* d_out, int out_size, void* d_ws, size_t ws_size,
                              hipStream_t stream) {
    const float* x   = (const float*)d_in[0];
    const int*   ei  = (const int*)d_in[1];
    const float* g1w = (const float*)d_in[2];
    const float* g1b = (const float*)d_in[3];
    const float* g2w = (const float*)d_in[4];
    const float* g2b = (const float*)d_in[5];
    const float* wih = (const float*)d_in[6];
    const float* whh = (const float*)d_in[7];
    const float* bih = (const float*)d_in[8];
    const float* bhh = (const float*)d_in[9];
    const float* dw1 = (const float*)d_in[10];
    const float* db1 = (const float*)d_in[11];
    const float* dw2 = (const float*)d_in[12];
    const float* db2 = (const float*)d_in[13];
    float* out = (float*)d_out;

    char* p = (char*)d_ws;
    auto alloc = [&](size_t bytes) {
        char* r = p;
        p += (bytes + 255) & ~(size_t)255;
        return r;
    };
    int*      counts   = (int*)     alloc(Nn * 4);
    int*      row_ptr  = (int*)     alloc((Nn + 1) * 4);
    int*      fill_ptr = (int*)     alloc((Nn + 1) * 4);
    float*    dinv     = (float*)   alloc(Nn * 4);
    float*    bsum     = (float*)   alloc(4 * Hn * 4);
    int*      col      = (int*)     alloc((En + Nn) * 4);
    float*    wgt      = (float*)   alloc((En + Nn) * 4);
    _Float16* wif      = (_Float16*)alloc(512 * 128 * 2);
    _Float16* whf      = (_Float16*)alloc(512 * 128 * 2);
    _Float16* g2wt     = (_Float16*)alloc(128 * 128 * 2);
    _Float16* d1f      = (_Float16*)alloc(64 * 128 * 2);
    float*    xt       = (float*)   alloc((size_t)Nn * 80 * 4);       // 3.2 MB
    _Float16* htf      = (_Float16*)alloc((size_t)ROWS * Hn * 2);     // 41 MB
    _Float16* h2f      = (_Float16*)alloc((size_t)ROWS * Hn * 2);     // 41 MB

    // counts must start at 0 (ws is poisoned 0xAA)
    hipMemsetAsync(counts, 0, Nn * 4, stream);

    // ---- fused setup: edge count + bsum + weight convert + x transpose + dw1 frag ----
    setup_kernel<<<1048, 256, 0, stream>>>(ei, bih, bhh, wih, whh, g2w, x, dw1,
                                           counts, bsum, wif, whf, g2wt, xt, d1f);
    scan_kernel<<<1, 1024, 0, stream>>>(counts, row_ptr, fill_ptr, dinv);
    fill_kernel<<<(Nn + En + 255) / 256, 256, 0, stream>>>(ei, dinv, fill_ptr, col, wgt);

    // ---- fused GCN: agg_x gather + GCN1 transform + GCN2 transform (MFMA) ----
    gcn2_fused_kernel<<<ROWS / 128, 256, 0, stream>>>(
        xt, row_ptr, col, wgt, g1w, g1b, g2wt, htf);

    // ---- GCN layer 2 aggregation (grid (Nn,4), 1 wave/block) ----
    gcn_agg2_kernel<<<dim3(Nn, 4), 64, 0, stream>>>(htf, row_ptr, col, wgt, g2b, h2f);

    // ---- fully fused LSTM + MFMA decoder ----
    lstm_fused6_kernel<<<MR / LROWS, 512, 0, stream>>>(
        h2f, wif, whf, bsum, d1f, db1, dw2, db2, out);
}